// Round 7
// baseline (321.441 us; speedup 1.0000x reference)
//
#include <hip/hip_runtime.h>
#include <cmath>

// ---------------------------------------------------------------------------
// g_s: 4x chained conv_transpose2d(k=5,s=2,p=2,op=1) + integer quant epilogue.
// Hermite: sum_j floor((round(w)+j)/split) == round(w) -> one conv per layer.
// Exact i8: weights round(w) in [-127,127]; activations (x-128) in i8; OOB
// halo = -128 so conv_i8 = conv_ref(x) - 128*tapsum[parity][co] (exact i32).
// v4: R=2 B-reuse per wave (LDS reads/MFMA halved), global_load_lds async
// staging for x-tile and B-slab (no ds_write, no VGPR round trip), xs stored
// in A-fragment order (conflict-free lane*16 reads).
// ---------------------------------------------------------------------------

typedef int int4v  __attribute__((ext_vector_type(4)));
typedef int int16v __attribute__((ext_vector_type(16)));

typedef __attribute__((address_space(1))) const void gl_cvoid;
typedef __attribute__((address_space(3))) void lds_void;

__device__ __forceinline__ void async_copy16(const void* g, void* l) {
    __builtin_amdgcn_global_load_lds((gl_cvoid*)g, (lds_void*)l, 16, 0, 0);
}

// tap id -> (ky,kx). Taps 0-8: EE; 9-14: EO; 15-20: OE; 21-24: OO.
__device__ __forceinline__ void tap_to_k(int t, int& ky, int& kx) {
    if (t < 9)       { int dy = t/3,  dx = t%3;                   ky = 4-2*dy; kx = 4-2*dx; }
    else if (t < 15) { int u = t-9;   int dy = u/2, dx = 1+(u&1);  ky = 4-2*dy; kx = 5-2*dx; }
    else if (t < 21) { int u = t-15;  int dy = 1+u/3, dx = u%3;    ky = 5-2*dy; kx = 4-2*dx; }
    else             { int u = t-21;  int dy = 1+u/2, dx = 1+(u&1); ky = 5-2*dy; kx = 5-2*dx; }
}

// f32 NCHW -> i8 (x-128) NHWC via LDS transpose; also fills the 16-B 0x80 slab
__global__ __launch_bounds__(256)
void convert_x_t(const float* __restrict__ x, signed char* __restrict__ xh,
                 signed char* __restrict__ slab, int C, int HW) {
    if (blockIdx.x == 0 && blockIdx.y == 0 && threadIdx.x < 16)
        slab[threadIdx.x] = (signed char)0x80;
    __shared__ float t[64][65];
    const int p0 = blockIdx.x * 64;
    const int c0 = blockIdx.y * 64;
    const int pL = threadIdx.x & 63;
    const int r0 = threadIdx.x >> 6;  // 0..3
    #pragma unroll
    for (int k = 0; k < 16; ++k) {
        int ciL = r0 * 16 + k;
        t[ciL][pL] = x[(size_t)(c0 + ciL) * HW + p0 + pL];
    }
    __syncthreads();
    #pragma unroll
    for (int k = 0; k < 16; ++k) {
        int pL2 = r0 * 16 + k;
        xh[(size_t)(p0 + pL2) * C + c0 + pL] = (signed char)((int)t[pL][pL2] - 128);
    }
}

// Coalesced pack for layers 1-3: one thread per (ci,co):
// byte addr = ((qs*NT + nb)*25 + t)*1024 + lane*16 + j
__global__ __launch_bounds__(256)
void pack3(const float* __restrict__ w1, const float* __restrict__ w2,
           const float* __restrict__ w3,
           signed char* __restrict__ p1, signed char* __restrict__ p2,
           signed char* __restrict__ p3) {
    const int layer = blockIdx.y;
    const float* w = (layer == 0) ? w1 : (layer == 1) ? w2 : w3;
    signed char* out = (layer == 0) ? p1 : (layer == 1) ? p2 : p3;
    const int Cin = (layer == 0) ? 320 : 192;
    const int Cout = 192, NT = 6;
    int idx = blockIdx.x * 256 + threadIdx.x;
    if (idx >= Cin * Cout) return;
    const int co = idx % Cout, ci = idx / Cout;
    const float* wr = w + (size_t)(ci * Cout + co) * 25;
    float v[25];
    #pragma unroll
    for (int k = 0; k < 25; ++k) {
        float t = rintf(wr[k]);
        v[k] = fminf(fmaxf(t, -128.0f), 127.0f);
    }
    const int qs = ci >> 5, half = (ci >> 4) & 1, j = ci & 15;
    const int nb = co >> 5, lane = half * 32 + (co & 31);
    size_t base = ((size_t)(qs * NT + nb) * 25) * 1024 + lane * 16 + j;
    #pragma unroll
    for (int t = 0; t < 25; ++t) {
        int ky, kx; tap_to_k(t, ky, kx);
        out[base + (size_t)t * 1024] = (signed char)(int)v[ky * 5 + kx];
    }
}

// final-layer pack: N-dim = (parity,co): column c = p*8+co (co<3 live).
__global__ void pack_w4_i8(const float* __restrict__ w, signed char* __restrict__ wpk) {
    int idx = blockIdx.x * blockDim.x + threadIdx.x;
    if (idx >= 6 * 9 * 64 * 16) return;
    int j    = idx & 15;
    int lane = (idx >> 4) & 63;
    int rem  = idx >> 10;
    int s9   = rem % 9;
    int qs   = rem / 9;
    int col  = lane & 31;
    int co   = col & 7;
    int p    = col >> 3;
    int py = p >> 1, px = p & 1;
    int dy = s9 / 3, dx = s9 % 3;
    int ci = qs * 32 + ((lane >> 5) << 4) + j;
    bool part = (py == 0 || dy >= 1) && (px == 0 || dx >= 1);
    float v = 0.0f;
    if (co < 3 && part) {
        int ky = py ? 5 - 2 * dy : 4 - 2 * dy;
        int kx = px ? 5 - 2 * dx : 4 - 2 * dx;
        v = rintf(w[(size_t)(ci * 3 + co) * 25 + ky * 5 + kx]);
        v = fminf(fmaxf(v, -128.0f), 127.0f);
    }
    wpk[idx] = (signed char)(int)v;
}

// fused tapsum: tapsum[p][co] = sum_{ky%2==py,kx%2==px} sum_ci round(w) (i32)
__global__ __launch_bounds__(64)
void tap4(const float* __restrict__ w1, const float* __restrict__ w2,
          const float* __restrict__ w3, const float* __restrict__ w4,
          int* __restrict__ t1, int* __restrict__ t2,
          int* __restrict__ t3, int* __restrict__ t4) {
    const int layer = blockIdx.y;
    const float* w = (layer == 0) ? w1 : (layer == 1) ? w2 : (layer == 2) ? w3 : w4;
    int* ts = (layer == 0) ? t1 : (layer == 1) ? t2 : (layer == 2) ? t3 : t4;
    const int Cin = (layer == 0) ? 320 : 192;
    const int Cout = (layer == 3) ? 3 : 192;
    const int i = blockIdx.x;
    if (i >= 4 * Cout) return;
    const int co = i % Cout, p = i / Cout;
    const int py = p >> 1, px = p & 1;
    const int nky = (5 - py + 1) >> 1;
    const int nkx = (5 - px + 1) >> 1;
    const int ntap = nky * nkx;
    int s = 0;
    for (int idx = threadIdx.x; idx < Cin * ntap; idx += 64) {
        const int ci = idx / ntap;
        const int u  = idx - ci * ntap;
        const int ky = py + 2 * (u / nkx);
        const int kx = px + 2 * (u % nkx);
        float v = rintf(w[(size_t)(ci * Cout + co) * 25 + ky * 5 + kx]);
        v = fminf(fmaxf(v, -128.0f), 127.0f);
        s += (int)v;
    }
    #pragma unroll
    for (int off = 32; off > 0; off >>= 1)
        s += __shfl_down(s, off, 64);
    if (threadIdx.x == 0) ts[i] = s;
}

// shift tables
__device__ __constant__ const int S_NT[9]     = {1,2,2,2,4,4,2,4,4};
__device__ __constant__ const int S_TAP[9][4] = {
    {0,0,0,0},{1,9,0,0},{2,10,0,0},{3,15,0,0},
    {4,11,16,21},{5,12,17,22},{6,18,0,0},{7,13,19,23},{8,14,20,24}};
__device__ __constant__ const int S_PAR[9][4] = {
    {0,0,0,0},{0,1,0,0},{0,1,0,0},{0,2,0,0},
    {0,1,2,3},{0,1,2,3},{0,2,0,0},{0,1,2,3},{0,1,2,3}};

// Layers 1-3 v4: 4 waves x R=2 subtiles -> 16 quad-rows x 16 quad-cols x 32 co.
// xs chunk layout: c = (rr*2 + g)*18 + cc  (rr=staged row 0..17, g=ci 16-group,
// cc=col 0..17), 16 B per chunk -> A-reads are contiguous lane*16 (no bank
// conflicts); staging via global_load_lds (wave-uniform base + lane*16).
__global__ __launch_bounds__(256, 3)
void deconv_v4(const signed char* __restrict__ xin, const signed char* __restrict__ wpk,
               const float* __restrict__ bias, const float* __restrict__ muls,
               const int* __restrict__ tsum, const signed char* __restrict__ slab,
               const float* __restrict__ relus, const int* __restrict__ dvds,
               const int* __restrict__ bitsp,
               int layer, int Cin, int Cout, int NT, int Hq, int Wq,
               signed char* __restrict__ outp) {
    constexpr int R = 2;
    __shared__ __align__(16) signed char xs[648 * 16];   // 18 rows x 2 g x 18 cols
    __shared__ __align__(16) signed char bs[25600];

    const int tid  = threadIdx.x;
    const int lane = tid & 63;
    const int wid  = tid >> 6;          // 0..3
    const int qx0  = blockIdx.y * 16;
    const int qy0  = blockIdx.z * 16;
    const int nb   = blockIdx.x;
    const int n0   = nb * 32;

    int16v acc[R][4];
    #pragma unroll
    for (int r = 0; r < R; ++r)
        #pragma unroll
        for (int p = 0; p < 4; ++p)
            #pragma unroll
            for (int e = 0; e < 16; ++e) acc[r][p][e] = 0;

    const int half   = lane >> 5;
    const int rowbit = (lane >> 4) & 1;
    const int col    = lane & 15;
    int rowb[R];
    #pragma unroll
    for (int r = 0; r < R; ++r) rowb[r] = (wid * R + r) * 2 + rowbit;

    for (int ck = 0; ck < Cin; ck += 32) {
        __syncthreads();
        const signed char* wslab = wpk + (size_t)((ck >> 5) * NT + nb) * 25600;
        // x-tile: 648 16-B chunks, A-fragment order
        #pragma unroll
        for (int j = 0; j < 3; ++j) {
            int base = j * 256 + wid * 64;
            int idx = base + lane;
            if (idx < 648) {
                int rr = idx / 36, rem = idx - rr * 36;
                int g = rem / 18, cc = rem - g * 18;
                int y = qy0 - 1 + rr, xx = qx0 - 1 + cc;
                const signed char* gp =
                    ((unsigned)y < (unsigned)Hq && (unsigned)xx < (unsigned)Wq)
                        ? &xin[((size_t)y * Wq + xx) * Cin + ck + g * 16] : slab;
                async_copy16(gp, &xs[base * 16]);
            }
        }
        // B slab: 1600 16-B chunks, linear
        #pragma unroll
        for (int j = 0; j < 7; ++j) {
            int base = j * 256 + wid * 64;
            if (base < 1600)
                async_copy16(&wslab[(base + lane) * 16], &bs[base * 16]);
        }
        __syncthreads();

        #pragma unroll
        for (int s9 = 0; s9 < 9; ++s9) {
            const int dy = s9 / 3, dx = s9 % 3;
            int4v a[R];
            #pragma unroll
            for (int r = 0; r < R; ++r)
                a[r] = *(const int4v*)&xs[(((rowb[r] + dy) * 2 + half) * 18 + col + dx) * 16];
            #pragma unroll
            for (int u = 0; u < 4; ++u) {
                if (u < S_NT[s9]) {
                    int4v b = *(const int4v*)&bs[S_TAP[s9][u] * 1024 + lane * 16];
                    const int p = S_PAR[s9][u];
                    #pragma unroll
                    for (int r = 0; r < R; ++r)
                        acc[r][p] = __builtin_amdgcn_mfma_i32_32x32x32_i8(a[r], b, acc[r][p], 0, 0, 0);
                }
            }
        }
    }

    // ----- quant epilogue (exact fp32 op sequence; proven absmax 0.0) --------
    const int dv = dvds[layer];
    float add1 = ldexpf(1.0f, dv - 10);
    float inv1 = ldexpf(1.0f, -(dv - 9));
    const float relu = relus[layer];
    const int sk = (layer == 1) ? 4 : 3;
    const float bitsv = ldexpf(1.0f, bitsp[0]) - 1.0f;
    float clp, scl;
    {
        #pragma clang fp contract(off)
        clp = rintf(bitsv / relu * 33554432.0f);
        scl = floorf((relu + ldexpf(1.0f, sk - 1)) * ldexpf(1.0f, -sk));
    }
    float add2 = ldexpf(1.0f, 24 - sk);
    float inv2 = ldexpf(1.0f, -(25 - sk));

    const int co = n0 + (lane & 31);
    float bq = rintf(bias[co]);
    float mm = muls[co];
    int fullp[4];
    #pragma unroll
    for (int p = 0; p < 4; ++p) fullp[p] = tsum[p * Cout + co];

    const int Wout = Wq * 2;

    #pragma unroll
    for (int r = 0; r < R; ++r) {
        #pragma unroll
        for (int p = 0; p < 4; ++p) {
            const int py = p >> 1, px = p & 1;
            #pragma unroll
            for (int reg = 0; reg < 16; ++reg) {
                const int mrow = (reg & 3) + 8 * (reg >> 2) + 4 * (lane >> 5);
                const int qy = qy0 + (wid * R + r) * 2 + (mrow >> 4);
                const int qx = qx0 + (mrow & 15);
                float v = (float)(acc[r][p][reg] + 128 * fullp[p]);
                {
                    #pragma clang fp contract(off)
                    v = (v + bq) * mm;
                    v = floorf((v + add1) * inv1);
                    v = fminf(fmaxf(v, 0.0f), clp);
                    v = floorf((v * scl + add2) * inv2);
                }
                const int oy = 2 * qy + py, ox = 2 * qx + px;
                outp[((size_t)oy * Wout + ox) * Cout + co] = (signed char)((int)v - 128);
            }
        }
    }
}

// Final layer v4: N = (parity,co) columns, 1 MFMA per shift, R=2.
__global__ __launch_bounds__(256, 4)
void deconv_final_v4(const signed char* __restrict__ xin, const signed char* __restrict__ wpk,
                     const float* __restrict__ bias, const float* __restrict__ muls,
                     const int* __restrict__ tsum, const signed char* __restrict__ slab,
                     const int* __restrict__ dvds,
                     int Cin, int Hq, int Wq, float* __restrict__ outp) {
    constexpr int R = 2;
    __shared__ __align__(16) signed char xs[648 * 16];
    __shared__ __align__(16) signed char bs[9216];

    const int tid  = threadIdx.x;
    const int lane = tid & 63;
    const int wid  = tid >> 6;
    const int qx0  = blockIdx.y * 16;
    const int qy0  = blockIdx.z * 16;

    int16v acc[R];
    #pragma unroll
    for (int r = 0; r < R; ++r)
        #pragma unroll
        for (int e = 0; e < 16; ++e) acc[r][e] = 0;

    const int half   = lane >> 5;
    const int rowbit = (lane >> 4) & 1;
    const int col    = lane & 15;
    int rowb[R];
    #pragma unroll
    for (int r = 0; r < R; ++r) rowb[r] = (wid * R + r) * 2 + rowbit;

    for (int ck = 0; ck < Cin; ck += 32) {
        __syncthreads();
        const signed char* wslab = wpk + (size_t)(ck >> 5) * 9216;
        #pragma unroll
        for (int j = 0; j < 3; ++j) {
            int base = j * 256 + wid * 64;
            int idx = base + lane;
            if (idx < 648) {
                int rr = idx / 36, rem = idx - rr * 36;
                int g = rem / 18, cc = rem - g * 18;
                int y = qy0 - 1 + rr, xx = qx0 - 1 + cc;
                const signed char* gp =
                    ((unsigned)y < (unsigned)Hq && (unsigned)xx < (unsigned)Wq)
                        ? &xin[((size_t)y * Wq + xx) * Cin + ck + g * 16] : slab;
                async_copy16(gp, &xs[base * 16]);
            }
        }
        #pragma unroll
        for (int j = 0; j < 3; ++j) {
            int base = j * 256 + wid * 64;
            if (base < 576)
                async_copy16(&wslab[(base + lane) * 16], &bs[base * 16]);
        }
        __syncthreads();

        #pragma unroll
        for (int s9 = 0; s9 < 9; ++s9) {
            const int dy = s9 / 3, dx = s9 % 3;
            int4v b = *(const int4v*)&bs[s9 * 1024 + lane * 16];
            #pragma unroll
            for (int r = 0; r < R; ++r) {
                int4v a = *(const int4v*)&xs[(((rowb[r] + dy) * 2 + half) * 18 + col + dx) * 16];
                acc[r] = __builtin_amdgcn_mfma_i32_32x32x32_i8(a, b, acc[r], 0, 0, 0);
            }
        }
    }

    const int dv = dvds[3];
    const float add1 = ldexpf(1.0f, dv - 9);
    const float inv1 = ldexpf(1.0f, -(dv - 8));

    const int coln = lane & 31;
    const int co = coln & 7;
    const int p  = coln >> 3;
    const int py = p >> 1, px = p & 1;
    const bool valid = (co < 3);
    float bq = 0.f, mm = 0.f;
    int fp = 0;
    if (valid) { bq = rintf(bias[co]); mm = muls[co]; fp = tsum[p * 3 + co]; }

    const int Wout = Wq * 2, Hout = Hq * 2;
    #pragma unroll
    for (int r = 0; r < R; ++r) {
        #pragma unroll
        for (int reg = 0; reg < 16; ++reg) {
            const int mrow = (reg & 3) + 8 * (reg >> 2) + 4 * (lane >> 5);
            const int qy = qy0 + (wid * R + r) * 2 + (mrow >> 4);
            const int qx = qx0 + (mrow & 15);
            float v = (float)(acc[r][reg] + 128 * fp);
            {
                #pragma clang fp contract(off)
                v = (v + bq) * mm;
                v = floorf((v + add1) * inv1);
                v = v / 255.0f;
            }
            if (valid) {
                const int oy = 2 * qy + py, ox = 2 * qx + px;
                outp[((size_t)co * Hout + oy) * Wout + ox] = v;
            }
        }
    }
}

extern "C" void kernel_launch(void* const* d_in, const int* in_sizes, int n_in,
                              void* d_out, int out_size, void* d_ws, size_t ws_size,
                              hipStream_t stream) {
    const float* x  = (const float*)d_in[0];
    const float* w1 = (const float*)d_in[1];
    const float* b1 = (const float*)d_in[2];
    const float* w2 = (const float*)d_in[3];
    const float* b2 = (const float*)d_in[4];
    const float* w3 = (const float*)d_in[5];
    const float* b3 = (const float*)d_in[6];
    const float* w4 = (const float*)d_in[7];
    const float* b4 = (const float*)d_in[8];
    const float* m0 = (const float*)d_in[9];
    const float* m1 = (const float*)d_in[10];
    const float* m2 = (const float*)d_in[11];
    const float* m3 = (const float*)d_in[12];
    const float* relus = (const float*)d_in[13];
    const int* dvds = (const int*)d_in[14];
    const int* bitsp = (const int*)d_in[15];

    signed char* wsb = (signed char*)d_ws;
    size_t o = 0;
    signed char* wpk1 = wsb + o; o += (size_t)10 * 6 * 25600;   // 1,536,000
    signed char* wpk2 = wsb + o; o += (size_t)6 * 6 * 25600;    //   921,600
    signed char* wpk3 = wsb + o; o += (size_t)6 * 6 * 25600;
    signed char* wpk4 = wsb + o; o += (size_t)6 * 9216;         //    55,296
    int* ts1 = (int*)(wsb + o); o += 4 * 192 * 4;
    int* ts2 = (int*)(wsb + o); o += 4 * 192 * 4;
    int* ts3 = (int*)(wsb + o); o += 4 * 192 * 4;
    int* ts4 = (int*)(wsb + o); o += 4 * 4 * 4;
    signed char* slab = wsb + o; o += 16;
    o = (o + 15) & ~(size_t)15;
    signed char* xh = wsb + o; o += (size_t)48 * 48 * 320;
    signed char* a1 = wsb + o; o += (size_t)96 * 96 * 192;
    signed char* a2 = wsb + o; o += (size_t)192 * 192 * 192;
    signed char* a3 = wsb + o; o += (size_t)384 * 384 * 192;

    convert_x_t<<<dim3(36, 5), 256, 0, stream>>>(x, xh, slab, 320, 48 * 48);
    pack3<<<dim3(240, 3), 256, 0, stream>>>(w1, w2, w3, wpk1, wpk2, wpk3);
    pack_w4_i8<<<(6 * 9 * 1024 + 255) / 256, 256, 0, stream>>>(w4, wpk4);
    tap4<<<dim3(768, 4), 64, 0, stream>>>(w1, w2, w3, w4, ts1, ts2, ts3, ts4);

    // layer 1: 48x48x320 -> 96x96x192   (16x16-quad tiles, 54 blocks)
    deconv_v4<<<dim3(6, 3, 3), 256, 0, stream>>>(
        xh, wpk1, b1, m0, ts1, slab, relus, dvds, bitsp, 0, 320, 192, 6, 48, 48, a1);
    // layer 2: 96x96x192 -> 192x192x192 (216 blocks)
    deconv_v4<<<dim3(6, 6, 6), 256, 0, stream>>>(
        a1, wpk2, b2, m1, ts2, slab, relus, dvds, bitsp, 1, 192, 192, 6, 96, 96, a2);
    // layer 3: 192x192x192 -> 384x384x192 (864 blocks)
    deconv_v4<<<dim3(6, 12, 12), 256, 0, stream>>>(
        a2, wpk3, b3, m2, ts3, slab, relus, dvds, bitsp, 2, 192, 192, 6, 192, 192, a3);
    // layer 4: 384x384x192 -> 3x768x768 (final, f32 NCHW, /255; 576 blocks)
    deconv_final_v4<<<dim3(1, 24, 24), 256, 0, stream>>>(
        a3, wpk4, b4, m3, ts4, slab, dvds, 192, 384, 384, (float*)d_out);
}

// Round 8
// 296.733 us; speedup vs baseline: 1.0833x; 1.0833x over previous
//
#include <hip/hip_runtime.h>
#include <cmath>

// ---------------------------------------------------------------------------
// g_s: 4x chained conv_transpose2d(k=5,s=2,p=2,op=1) + integer quant epilogue.
// Hermite: sum_j floor((round(w)+j)/split) == round(w) -> one conv per layer.
// Exact i8: weights round(w) in [-127,127]; activations (x-128) in i8; OOB
// halo = -128 so conv_i8 = conv_ref(x) - 128*tapsum[parity][co] (exact i32).
// v5 = v3 staging (plain loads; global_load_lds w/ scattered lanes kills L2
// coalescing -> 6x FETCH, measured r7) + v4 R=2 geometry (B-frag feeds 2
// MFMAs; 172 ds_reads per 200 MFMAs vs 272).
// ---------------------------------------------------------------------------

typedef int int4v  __attribute__((ext_vector_type(4)));
typedef int int16v __attribute__((ext_vector_type(16)));

// tap id -> (ky,kx). Taps 0-8: EE; 9-14: EO; 15-20: OE; 21-24: OO.
__device__ __forceinline__ void tap_to_k(int t, int& ky, int& kx) {
    if (t < 9)       { int dy = t/3,  dx = t%3;                   ky = 4-2*dy; kx = 4-2*dx; }
    else if (t < 15) { int u = t-9;   int dy = u/2, dx = 1+(u&1);  ky = 4-2*dy; kx = 5-2*dx; }
    else if (t < 21) { int u = t-15;  int dy = 1+u/3, dx = u%3;    ky = 5-2*dy; kx = 4-2*dx; }
    else             { int u = t-21;  int dy = 1+u/2, dx = 1+(u&1); ky = 5-2*dy; kx = 5-2*dx; }
}

// f32 NCHW -> i8 (x-128) NHWC via LDS transpose (both sides coalesced)
__global__ __launch_bounds__(256)
void convert_x_t(const float* __restrict__ x, signed char* __restrict__ xh,
                 int C, int HW) {
    __shared__ float t[64][65];
    const int p0 = blockIdx.x * 64;
    const int c0 = blockIdx.y * 64;
    const int pL = threadIdx.x & 63;
    const int r0 = threadIdx.x >> 6;  // 0..3
    #pragma unroll
    for (int k = 0; k < 16; ++k) {
        int ciL = r0 * 16 + k;
        t[ciL][pL] = x[(size_t)(c0 + ciL) * HW + p0 + pL];
    }
    __syncthreads();
    #pragma unroll
    for (int k = 0; k < 16; ++k) {
        int pL2 = r0 * 16 + k;
        xh[(size_t)(p0 + pL2) * C + c0 + pL] = (signed char)((int)t[pL][pL2] - 128);
    }
}

// Coalesced pack for layers 1-3: one thread per (ci,co):
// byte addr = ((qs*NT + nb)*25 + t)*1024 + lane*16 + j
__global__ __launch_bounds__(256)
void pack3(const float* __restrict__ w1, const float* __restrict__ w2,
           const float* __restrict__ w3,
           signed char* __restrict__ p1, signed char* __restrict__ p2,
           signed char* __restrict__ p3) {
    const int layer = blockIdx.y;
    const float* w = (layer == 0) ? w1 : (layer == 1) ? w2 : w3;
    signed char* out = (layer == 0) ? p1 : (layer == 1) ? p2 : p3;
    const int Cin = (layer == 0) ? 320 : 192;
    const int Cout = 192, NT = 6;
    int idx = blockIdx.x * 256 + threadIdx.x;
    if (idx >= Cin * Cout) return;
    const int co = idx % Cout, ci = idx / Cout;
    const float* wr = w + (size_t)(ci * Cout + co) * 25;
    float v[25];
    #pragma unroll
    for (int k = 0; k < 25; ++k) {
        float t = rintf(wr[k]);
        v[k] = fminf(fmaxf(t, -128.0f), 127.0f);
    }
    const int qs = ci >> 5, half = (ci >> 4) & 1, j = ci & 15;
    const int nb = co >> 5, lane = half * 32 + (co & 31);
    size_t base = ((size_t)(qs * NT + nb) * 25) * 1024 + lane * 16 + j;
    #pragma unroll
    for (int t = 0; t < 25; ++t) {
        int ky, kx; tap_to_k(t, ky, kx);
        out[base + (size_t)t * 1024] = (signed char)(int)v[ky * 5 + kx];
    }
}

// final-layer pack: N-dim = (parity,co): column c = p*8+co (co<3 live).
__global__ void pack_w4_i8(const float* __restrict__ w, signed char* __restrict__ wpk) {
    int idx = blockIdx.x * blockDim.x + threadIdx.x;
    if (idx >= 6 * 9 * 64 * 16) return;
    int j    = idx & 15;
    int lane = (idx >> 4) & 63;
    int rem  = idx >> 10;
    int s9   = rem % 9;
    int qs   = rem / 9;
    int col  = lane & 31;
    int co   = col & 7;
    int p    = col >> 3;
    int py = p >> 1, px = p & 1;
    int dy = s9 / 3, dx = s9 % 3;
    int ci = qs * 32 + ((lane >> 5) << 4) + j;
    bool part = (py == 0 || dy >= 1) && (px == 0 || dx >= 1);
    float v = 0.0f;
    if (co < 3 && part) {
        int ky = py ? 5 - 2 * dy : 4 - 2 * dy;
        int kx = px ? 5 - 2 * dx : 4 - 2 * dx;
        v = rintf(w[(size_t)(ci * 3 + co) * 25 + ky * 5 + kx]);
        v = fminf(fmaxf(v, -128.0f), 127.0f);
    }
    wpk[idx] = (signed char)(int)v;
}

// fused tapsum: tapsum[p][co] = sum_{ky%2==py,kx%2==px} sum_ci round(w) (i32)
__global__ __launch_bounds__(64)
void tap4(const float* __restrict__ w1, const float* __restrict__ w2,
          const float* __restrict__ w3, const float* __restrict__ w4,
          int* __restrict__ t1, int* __restrict__ t2,
          int* __restrict__ t3, int* __restrict__ t4) {
    const int layer = blockIdx.y;
    const float* w = (layer == 0) ? w1 : (layer == 1) ? w2 : (layer == 2) ? w3 : w4;
    int* ts = (layer == 0) ? t1 : (layer == 1) ? t2 : (layer == 2) ? t3 : t4;
    const int Cin = (layer == 0) ? 320 : 192;
    const int Cout = (layer == 3) ? 3 : 192;
    const int i = blockIdx.x;
    if (i >= 4 * Cout) return;
    const int co = i % Cout, p = i / Cout;
    const int py = p >> 1, px = p & 1;
    const int nky = (5 - py + 1) >> 1;
    const int nkx = (5 - px + 1) >> 1;
    const int ntap = nky * nkx;
    int s = 0;
    for (int idx = threadIdx.x; idx < Cin * ntap; idx += 64) {
        const int ci = idx / ntap;
        const int u  = idx - ci * ntap;
        const int ky = py + 2 * (u / nkx);
        const int kx = px + 2 * (u % nkx);
        float v = rintf(w[(size_t)(ci * Cout + co) * 25 + ky * 5 + kx]);
        v = fminf(fmaxf(v, -128.0f), 127.0f);
        s += (int)v;
    }
    #pragma unroll
    for (int off = 32; off > 0; off >>= 1)
        s += __shfl_down(s, off, 64);
    if (threadIdx.x == 0) ts[i] = s;
}

// shift tables
__device__ __constant__ const int S_NT[9]     = {1,2,2,2,4,4,2,4,4};
__device__ __constant__ const int S_TAP[9][4] = {
    {0,0,0,0},{1,9,0,0},{2,10,0,0},{3,15,0,0},
    {4,11,16,21},{5,12,17,22},{6,18,0,0},{7,13,19,23},{8,14,20,24}};
__device__ __constant__ const int S_PAR[9][4] = {
    {0,0,0,0},{0,1,0,0},{0,1,0,0},{0,2,0,0},
    {0,1,2,3},{0,1,2,3},{0,2,0,0},{0,1,2,3},{0,1,2,3}};

// Layers 1-3 v5: 4 waves x R=2 subtiles -> 16 quad-rows x 16 quad-cols x 32 co.
// KC=32; xs pixel stride 48 B (v3-proven); B slab (25 KB) staged in LDS.
__global__ __launch_bounds__(256, 3)
void deconv_v5(const signed char* __restrict__ xin, const signed char* __restrict__ wpk,
               const float* __restrict__ bias, const float* __restrict__ muls,
               const int* __restrict__ tsum,
               const float* __restrict__ relus, const int* __restrict__ dvds,
               const int* __restrict__ bitsp,
               int layer, int Cin, int Cout, int NT, int Hq, int Wq,
               signed char* __restrict__ outp) {
    constexpr int R = 2;
    constexpr int NPIX = 18 * 18;
    __shared__ __align__(16) signed char xs[NPIX * 48];
    __shared__ __align__(16) signed char bs[25600];

    const int tid  = threadIdx.x;
    const int lane = tid & 63;
    const int wid  = tid >> 6;          // 0..3
    const int qx0  = blockIdx.y * 16;
    const int qy0  = blockIdx.z * 16;
    const int nb   = blockIdx.x;
    const int n0   = nb * 32;

    int16v acc[R][4];
    #pragma unroll
    for (int r = 0; r < R; ++r)
        #pragma unroll
        for (int p = 0; p < 4; ++p)
            #pragma unroll
            for (int e = 0; e < 16; ++e) acc[r][p][e] = 0;

    const int half   = lane >> 5;
    const int rowbit = (lane >> 4) & 1;
    const int col    = lane & 15;
    int p0[R];
    #pragma unroll
    for (int r = 0; r < R; ++r)
        p0[r] = ((wid * R + r) * 2 + rowbit) * 18 + col;

    for (int ck = 0; ck < Cin; ck += 32) {
        __syncthreads();
        const signed char* wslab = wpk + (size_t)((ck >> 5) * NT + nb) * 25600;
        for (int i = tid; i < NPIX * 2 + 1600; i += 256) {
            if (i < NPIX * 2) {
                int pix = i >> 1, g = i & 1;
                int rr = pix / 18, cc = pix - rr * 18;
                int y = qy0 - 1 + rr, x = qx0 - 1 + cc;
                int4v v = {(int)0x80808080, (int)0x80808080,
                           (int)0x80808080, (int)0x80808080};
                if ((unsigned)y < (unsigned)Hq && (unsigned)x < (unsigned)Wq)
                    v = *(const int4v*)&xin[((size_t)y * Wq + x) * Cin + ck + g * 16];
                *(int4v*)&xs[pix * 48 + g * 16] = v;
            } else {
                int i2 = i - NPIX * 2;
                *(int4v*)&bs[i2 * 16] = *(const int4v*)&wslab[i2 * 16];
            }
        }
        __syncthreads();

        #pragma unroll
        for (int s9 = 0; s9 < 9; ++s9) {
            const int dy = s9 / 3, dx = s9 % 3;
            int4v a[R];
            #pragma unroll
            for (int r = 0; r < R; ++r)
                a[r] = *(const int4v*)&xs[(p0[r] + dy * 18 + dx) * 48 + half * 16];
            #pragma unroll
            for (int u = 0; u < 4; ++u) {
                if (u < S_NT[s9]) {
                    int4v b = *(const int4v*)&bs[S_TAP[s9][u] * 1024 + lane * 16];
                    const int p = S_PAR[s9][u];
                    #pragma unroll
                    for (int r = 0; r < R; ++r)
                        acc[r][p] = __builtin_amdgcn_mfma_i32_32x32x32_i8(a[r], b, acc[r][p], 0, 0, 0);
                }
            }
        }
    }

    // ----- quant epilogue (exact fp32 op sequence; proven absmax 0.0) --------
    const int dv = dvds[layer];
    float add1 = ldexpf(1.0f, dv - 10);
    float inv1 = ldexpf(1.0f, -(dv - 9));
    const float relu = relus[layer];
    const int sk = (layer == 1) ? 4 : 3;
    const float bitsv = ldexpf(1.0f, bitsp[0]) - 1.0f;
    float clp, scl;
    {
        #pragma clang fp contract(off)
        clp = rintf(bitsv / relu * 33554432.0f);
        scl = floorf((relu + ldexpf(1.0f, sk - 1)) * ldexpf(1.0f, -sk));
    }
    float add2 = ldexpf(1.0f, 24 - sk);
    float inv2 = ldexpf(1.0f, -(25 - sk));

    const int co = n0 + (lane & 31);
    float bq = rintf(bias[co]);
    float mm = muls[co];
    int fullp[4];
    #pragma unroll
    for (int p = 0; p < 4; ++p) fullp[p] = tsum[p * Cout + co];

    const int Wout = Wq * 2;

    #pragma unroll
    for (int r = 0; r < R; ++r) {
        #pragma unroll
        for (int p = 0; p < 4; ++p) {
            const int py = p >> 1, px = p & 1;
            #pragma unroll
            for (int reg = 0; reg < 16; ++reg) {
                const int mrow = (reg & 3) + 8 * (reg >> 2) + 4 * (lane >> 5);
                const int qy = qy0 + (wid * R + r) * 2 + (mrow >> 4);
                const int qx = qx0 + (mrow & 15);
                float v = (float)(acc[r][p][reg] + 128 * fullp[p]);
                {
                    #pragma clang fp contract(off)
                    v = (v + bq) * mm;
                    v = floorf((v + add1) * inv1);
                    v = fminf(fmaxf(v, 0.0f), clp);
                    v = floorf((v * scl + add2) * inv2);
                }
                const int oy = 2 * qy + py, ox = 2 * qx + px;
                outp[((size_t)oy * Wout + ox) * Cout + co] = (signed char)((int)v - 128);
            }
        }
    }
}

// Final layer v5: N = (parity,co) columns, 1 MFMA per shift, R=2, v3 staging.
__global__ __launch_bounds__(256, 4)
void deconv_final_v5(const signed char* __restrict__ xin, const signed char* __restrict__ wpk,
                     const float* __restrict__ bias, const float* __restrict__ muls,
                     const int* __restrict__ tsum, const int* __restrict__ dvds,
                     int Cin, int Hq, int Wq, float* __restrict__ outp) {
    constexpr int R = 2;
    constexpr int NPIX = 18 * 18;
    __shared__ __align__(16) signed char xs[NPIX * 48];
    __shared__ __align__(16) signed char bs[9216];

    const int tid  = threadIdx.x;
    const int lane = tid & 63;
    const int wid  = tid >> 6;
    const int qx0  = blockIdx.y * 16;
    const int qy0  = blockIdx.z * 16;

    int16v acc[R];
    #pragma unroll
    for (int r = 0; r < R; ++r)
        #pragma unroll
        for (int e = 0; e < 16; ++e) acc[r][e] = 0;

    const int half   = lane >> 5;
    const int rowbit = (lane >> 4) & 1;
    const int col    = lane & 15;
    int p0[R];
    #pragma unroll
    for (int r = 0; r < R; ++r)
        p0[r] = ((wid * R + r) * 2 + rowbit) * 18 + col;

    for (int ck = 0; ck < Cin; ck += 32) {
        __syncthreads();
        const signed char* wslab = wpk + (size_t)(ck >> 5) * 9216;
        for (int i = tid; i < NPIX * 2 + 576; i += 256) {
            if (i < NPIX * 2) {
                int pix = i >> 1, g = i & 1;
                int rr = pix / 18, cc = pix - rr * 18;
                int y = qy0 - 1 + rr, x = qx0 - 1 + cc;
                int4v v = {(int)0x80808080, (int)0x80808080,
                           (int)0x80808080, (int)0x80808080};
                if ((unsigned)y < (unsigned)Hq && (unsigned)x < (unsigned)Wq)
                    v = *(const int4v*)&xin[((size_t)y * Wq + x) * Cin + ck + g * 16];
                *(int4v*)&xs[pix * 48 + g * 16] = v;
            } else {
                int i2 = i - NPIX * 2;
                *(int4v*)&bs[i2 * 16] = *(const int4v*)&wslab[i2 * 16];
            }
        }
        __syncthreads();

        #pragma unroll
        for (int s9 = 0; s9 < 9; ++s9) {
            const int dy = s9 / 3, dx = s9 % 3;
            int4v b = *(const int4v*)&bs[s9 * 1024 + lane * 16];
            #pragma unroll
            for (int r = 0; r < R; ++r) {
                int4v a = *(const int4v*)&xs[(p0[r] + dy * 18 + dx) * 48 + half * 16];
                acc[r] = __builtin_amdgcn_mfma_i32_32x32x32_i8(a, b, acc[r], 0, 0, 0);
            }
        }
    }

    const int dv = dvds[3];
    const float add1 = ldexpf(1.0f, dv - 9);
    const float inv1 = ldexpf(1.0f, -(dv - 8));

    const int coln = lane & 31;
    const int co = coln & 7;
    const int p  = coln >> 3;
    const int py = p >> 1, px = p & 1;
    const bool valid = (co < 3);
    float bq = 0.f, mm = 0.f;
    int fp = 0;
    if (valid) { bq = rintf(bias[co]); mm = muls[co]; fp = tsum[p * 3 + co]; }

    const int Wout = Wq * 2, Hout = Hq * 2;
    #pragma unroll
    for (int r = 0; r < R; ++r) {
        #pragma unroll
        for (int reg = 0; reg < 16; ++reg) {
            const int mrow = (reg & 3) + 8 * (reg >> 2) + 4 * (lane >> 5);
            const int qy = qy0 + (wid * R + r) * 2 + (mrow >> 4);
            const int qx = qx0 + (mrow & 15);
            float v = (float)(acc[r][reg] + 128 * fp);
            {
                #pragma clang fp contract(off)
                v = (v + bq) * mm;
                v = floorf((v + add1) * inv1);
                v = v / 255.0f;
            }
            if (valid) {
                const int oy = 2 * qy + py, ox = 2 * qx + px;
                outp[((size_t)co * Hout + oy) * Wout + ox] = v;
            }
        }
    }
}

extern "C" void kernel_launch(void* const* d_in, const int* in_sizes, int n_in,
                              void* d_out, int out_size, void* d_ws, size_t ws_size,
                              hipStream_t stream) {
    const float* x  = (const float*)d_in[0];
    const float* w1 = (const float*)d_in[1];
    const float* b1 = (const float*)d_in[2];
    const float* w2 = (const float*)d_in[3];
    const float* b2 = (const float*)d_in[4];
    const float* w3 = (const float*)d_in[5];
    const float* b3 = (const float*)d_in[6];
    const float* w4 = (const float*)d_in[7];
    const float* b4 = (const float*)d_in[8];
    const float* m0 = (const float*)d_in[9];
    const float* m1 = (const float*)d_in[10];
    const float* m2 = (const float*)d_in[11];
    const float* m3 = (const float*)d_in[12];
    const float* relus = (const float*)d_in[13];
    const int* dvds = (const int*)d_in[14];
    const int* bitsp = (const int*)d_in[15];

    signed char* wsb = (signed char*)d_ws;
    size_t o = 0;
    signed char* wpk1 = wsb + o; o += (size_t)10 * 6 * 25600;   // 1,536,000
    signed char* wpk2 = wsb + o; o += (size_t)6 * 6 * 25600;    //   921,600
    signed char* wpk3 = wsb + o; o += (size_t)6 * 6 * 25600;
    signed char* wpk4 = wsb + o; o += (size_t)6 * 9216;         //    55,296
    int* ts1 = (int*)(wsb + o); o += 4 * 192 * 4;
    int* ts2 = (int*)(wsb + o); o += 4 * 192 * 4;
    int* ts3 = (int*)(wsb + o); o += 4 * 192 * 4;
    int* ts4 = (int*)(wsb + o); o += 4 * 4 * 4;
    o = (o + 15) & ~(size_t)15;
    signed char* xh = wsb + o; o += (size_t)48 * 48 * 320;
    signed char* a1 = wsb + o; o += (size_t)96 * 96 * 192;
    signed char* a2 = wsb + o; o += (size_t)192 * 192 * 192;
    signed char* a3 = wsb + o; o += (size_t)384 * 384 * 192;

    convert_x_t<<<dim3(36, 5), 256, 0, stream>>>(x, xh, 320, 48 * 48);
    pack3<<<dim3(240, 3), 256, 0, stream>>>(w1, w2, w3, wpk1, wpk2, wpk3);
    pack_w4_i8<<<(6 * 9 * 1024 + 255) / 256, 256, 0, stream>>>(w4, wpk4);
    tap4<<<dim3(768, 4), 64, 0, stream>>>(w1, w2, w3, w4, ts1, ts2, ts3, ts4);

    // layer 1: 48x48x320 -> 96x96x192   (16x16-quad tiles, 54 blocks)
    deconv_v5<<<dim3(6, 3, 3), 256, 0, stream>>>(
        xh, wpk1, b1, m0, ts1, relus, dvds, bitsp, 0, 320, 192, 6, 48, 48, a1);
    // layer 2: 96x96x192 -> 192x192x192 (216 blocks)
    deconv_v5<<<dim3(6, 6, 6), 256, 0, stream>>>(
        a1, wpk2, b2, m1, ts2, relus, dvds, bitsp, 1, 192, 192, 6, 96, 96, a2);
    // layer 3: 192x192x192 -> 384x384x192 (864 blocks)
    deconv_v5<<<dim3(6, 12, 12), 256, 0, stream>>>(
        a2, wpk3, b3, m2, ts3, relus, dvds, bitsp, 2, 192, 192, 6, 192, 192, a3);
    // layer 4: 384x384x192 -> 3x768x768 (final, f32 NCHW, /255; 576 blocks)
    deconv_final_v5<<<dim3(1, 24, 24), 256, 0, stream>>>(
        a3, wpk4, b4, m3, ts4, dvds, 192, 384, 384, (float*)d_out);
}

// Round 9
// 235.610 us; speedup vs baseline: 1.3643x; 1.2594x over previous
//
#include <hip/hip_runtime.h>
#include <cmath>

// ---------------------------------------------------------------------------
// g_s: 4x chained conv_transpose2d(k=5,s=2,p=2,op=1) + integer quant epilogue.
// Hermite: sum_j floor((round(w)+j)/split) == round(w) -> one conv per layer.
// Exact i8: weights round(w) in [-127,127]; activations (x-128) in i8; OOB
// halo = -128 so conv_i8 = conv_ref(x) - 128*tapsum[parity][co] (exact i32).
// v6: register-prefetch software pipeline (load chunk k+1 into VGPRs while
// computing chunk k -> global latency off the barrier critical path) +
// 512-thr blocks for L3/L4 (4 waves/SIMD co-resident). Staging uses plain
// per-lane loads (global_load_lds w/ scattered lanes kills L2 coalescing, r7).
// ---------------------------------------------------------------------------

typedef int int4v  __attribute__((ext_vector_type(4)));
typedef int int16v __attribute__((ext_vector_type(16)));

// tap id -> (ky,kx). Taps 0-8: EE; 9-14: EO; 15-20: OE; 21-24: OO.
__device__ __forceinline__ void tap_to_k(int t, int& ky, int& kx) {
    if (t < 9)       { int dy = t/3,  dx = t%3;                   ky = 4-2*dy; kx = 4-2*dx; }
    else if (t < 15) { int u = t-9;   int dy = u/2, dx = 1+(u&1);  ky = 4-2*dy; kx = 5-2*dx; }
    else if (t < 21) { int u = t-15;  int dy = 1+u/3, dx = u%3;    ky = 5-2*dy; kx = 4-2*dx; }
    else             { int u = t-21;  int dy = 1+u/2, dx = 1+(u&1); ky = 5-2*dy; kx = 5-2*dx; }
}

// f32 NCHW -> i8 (x-128) NHWC via LDS transpose (both sides coalesced)
__global__ __launch_bounds__(256)
void convert_x_t(const float* __restrict__ x, signed char* __restrict__ xh,
                 int C, int HW) {
    __shared__ float t[64][65];
    const int p0 = blockIdx.x * 64;
    const int c0 = blockIdx.y * 64;
    const int pL = threadIdx.x & 63;
    const int r0 = threadIdx.x >> 6;  // 0..3
    #pragma unroll
    for (int k = 0; k < 16; ++k) {
        int ciL = r0 * 16 + k;
        t[ciL][pL] = x[(size_t)(c0 + ciL) * HW + p0 + pL];
    }
    __syncthreads();
    #pragma unroll
    for (int k = 0; k < 16; ++k) {
        int pL2 = r0 * 16 + k;
        xh[(size_t)(p0 + pL2) * C + c0 + pL] = (signed char)((int)t[pL][pL2] - 128);
    }
}

// Coalesced pack for layers 1-3: one thread per (ci,co):
// byte addr = ((qs*NT + nb)*25 + t)*1024 + lane*16 + j
__global__ __launch_bounds__(256)
void pack3(const float* __restrict__ w1, const float* __restrict__ w2,
           const float* __restrict__ w3,
           signed char* __restrict__ p1, signed char* __restrict__ p2,
           signed char* __restrict__ p3) {
    const int layer = blockIdx.y;
    const float* w = (layer == 0) ? w1 : (layer == 1) ? w2 : w3;
    signed char* out = (layer == 0) ? p1 : (layer == 1) ? p2 : p3;
    const int Cin = (layer == 0) ? 320 : 192;
    const int Cout = 192, NT = 6;
    int idx = blockIdx.x * 256 + threadIdx.x;
    if (idx >= Cin * Cout) return;
    const int co = idx % Cout, ci = idx / Cout;
    const float* wr = w + (size_t)(ci * Cout + co) * 25;
    float v[25];
    #pragma unroll
    for (int k = 0; k < 25; ++k) {
        float t = rintf(wr[k]);
        v[k] = fminf(fmaxf(t, -128.0f), 127.0f);
    }
    const int qs = ci >> 5, half = (ci >> 4) & 1, j = ci & 15;
    const int nb = co >> 5, lane = half * 32 + (co & 31);
    size_t base = ((size_t)(qs * NT + nb) * 25) * 1024 + lane * 16 + j;
    #pragma unroll
    for (int t = 0; t < 25; ++t) {
        int ky, kx; tap_to_k(t, ky, kx);
        out[base + (size_t)t * 1024] = (signed char)(int)v[ky * 5 + kx];
    }
}

// final-layer pack: N-dim = (parity,co): column c = p*8+co (co<3 live).
__global__ void pack_w4_i8(const float* __restrict__ w, signed char* __restrict__ wpk) {
    int idx = blockIdx.x * blockDim.x + threadIdx.x;
    if (idx >= 6 * 9 * 64 * 16) return;
    int j    = idx & 15;
    int lane = (idx >> 4) & 63;
    int rem  = idx >> 10;
    int s9   = rem % 9;
    int qs   = rem / 9;
    int col  = lane & 31;
    int co   = col & 7;
    int p    = col >> 3;
    int py = p >> 1, px = p & 1;
    int dy = s9 / 3, dx = s9 % 3;
    int ci = qs * 32 + ((lane >> 5) << 4) + j;
    bool part = (py == 0 || dy >= 1) && (px == 0 || dx >= 1);
    float v = 0.0f;
    if (co < 3 && part) {
        int ky = py ? 5 - 2 * dy : 4 - 2 * dy;
        int kx = px ? 5 - 2 * dx : 4 - 2 * dx;
        v = rintf(w[(size_t)(ci * 3 + co) * 25 + ky * 5 + kx]);
        v = fminf(fmaxf(v, -128.0f), 127.0f);
    }
    wpk[idx] = (signed char)(int)v;
}

// fused tapsum: tapsum[p][co] = sum_{ky%2==py,kx%2==px} sum_ci round(w) (i32)
__global__ __launch_bounds__(64)
void tap4(const float* __restrict__ w1, const float* __restrict__ w2,
          const float* __restrict__ w3, const float* __restrict__ w4,
          int* __restrict__ t1, int* __restrict__ t2,
          int* __restrict__ t3, int* __restrict__ t4) {
    const int layer = blockIdx.y;
    const float* w = (layer == 0) ? w1 : (layer == 1) ? w2 : (layer == 2) ? w3 : w4;
    int* ts = (layer == 0) ? t1 : (layer == 1) ? t2 : (layer == 2) ? t3 : t4;
    const int Cin = (layer == 0) ? 320 : 192;
    const int Cout = (layer == 3) ? 3 : 192;
    const int i = blockIdx.x;
    if (i >= 4 * Cout) return;
    const int co = i % Cout, p = i / Cout;
    const int py = p >> 1, px = p & 1;
    const int nky = (5 - py + 1) >> 1;
    const int nkx = (5 - px + 1) >> 1;
    const int ntap = nky * nkx;
    int s = 0;
    for (int idx = threadIdx.x; idx < Cin * ntap; idx += 64) {
        const int ci = idx / ntap;
        const int u  = idx - ci * ntap;
        const int ky = py + 2 * (u / nkx);
        const int kx = px + 2 * (u % nkx);
        float v = rintf(w[(size_t)(ci * Cout + co) * 25 + ky * 5 + kx]);
        v = fminf(fmaxf(v, -128.0f), 127.0f);
        s += (int)v;
    }
    #pragma unroll
    for (int off = 32; off > 0; off >>= 1)
        s += __shfl_down(s, off, 64);
    if (threadIdx.x == 0) ts[i] = s;
}

// shift tables
__device__ __constant__ const int S_NT[9]     = {1,2,2,2,4,4,2,4,4};
__device__ __constant__ const int S_TAP[9][4] = {
    {0,0,0,0},{1,9,0,0},{2,10,0,0},{3,15,0,0},
    {4,11,16,21},{5,12,17,22},{6,18,0,0},{7,13,19,23},{8,14,20,24}};
__device__ __constant__ const int S_PAR[9][4] = {
    {0,0,0,0},{0,1,0,0},{0,1,0,0},{0,2,0,0},
    {0,1,2,3},{0,1,2,3},{0,2,0,0},{0,1,2,3},{0,1,2,3}};

// Layers 1-3 v6: MW waves x R=2 subtiles -> (MW*4) quad-rows x 16 cols x 32 co.
// Register-prefetch pipeline over KC=32 chunks.
template<int MW>
__global__ __launch_bounds__(MW * 64)
void deconv_v6(const signed char* __restrict__ xin, const signed char* __restrict__ wpk,
               const float* __restrict__ bias, const float* __restrict__ muls,
               const int* __restrict__ tsum,
               const float* __restrict__ relus, const int* __restrict__ dvds,
               const int* __restrict__ bitsp,
               int layer, int Cin, int Cout, int NT, int Hq, int Wq,
               signed char* __restrict__ outp) {
    constexpr int R = 2;
    constexpr int NROW = MW * R * 2 + 2;
    constexpr int NPIX = NROW * 18;
    constexpr int THREADS = MW * 64;
    constexpr int XC = NPIX * 2;
    constexpr int XI = (XC + THREADS - 1) / THREADS;
    constexpr int BC = 1600;
    constexpr int BI = (BC + THREADS - 1) / THREADS;

    __shared__ __align__(16) signed char xs[NPIX * 48];
    __shared__ __align__(16) signed char bs[25600];

    const int tid  = threadIdx.x;
    const int lane = tid & 63;
    const int wid  = tid >> 6;
    const int qx0  = blockIdx.y * 16;
    const int qy0  = blockIdx.z * (MW * R * 2);
    const int nb   = blockIdx.x;
    const int n0   = nb * 32;

    int16v acc[R][4];
    #pragma unroll
    for (int r = 0; r < R; ++r)
        #pragma unroll
        for (int p = 0; p < 4; ++p)
            #pragma unroll
            for (int e = 0; e < 16; ++e) acc[r][p][e] = 0;

    const int half   = lane >> 5;
    const int rowbit = (lane >> 4) & 1;
    const int col    = lane & 15;
    int p0[R];
    #pragma unroll
    for (int r = 0; r < R; ++r)
        p0[r] = ((wid * R + r) * 2 + rowbit) * 18 + col;

    int4v xreg[XI], breg[BI];

    auto load_chunk = [&](int ck) {
        const signed char* wslab = wpk + (size_t)((ck >> 5) * NT + nb) * 25600;
        #pragma unroll
        for (int t = 0; t < XI; ++t) {
            int i = tid + t * THREADS;
            if (i < XC) {
                int pix = i >> 1, g = i & 1;
                int rr = pix / 18, cc = pix - rr * 18;
                int y = qy0 - 1 + rr, xx = qx0 - 1 + cc;
                int4v v = {(int)0x80808080, (int)0x80808080,
                           (int)0x80808080, (int)0x80808080};
                if ((unsigned)y < (unsigned)Hq && (unsigned)xx < (unsigned)Wq)
                    v = *(const int4v*)&xin[((size_t)y * Wq + xx) * Cin + ck + g * 16];
                xreg[t] = v;
            }
        }
        #pragma unroll
        for (int t = 0; t < BI; ++t) {
            int i = tid + t * THREADS;
            if (i < BC) breg[t] = *(const int4v*)&wslab[(size_t)i * 16];
        }
    };
    auto store_chunk = [&]() {
        #pragma unroll
        for (int t = 0; t < XI; ++t) {
            int i = tid + t * THREADS;
            if (i < XC) {
                int pix = i >> 1, g = i & 1;
                *(int4v*)&xs[pix * 48 + g * 16] = xreg[t];
            }
        }
        #pragma unroll
        for (int t = 0; t < BI; ++t) {
            int i = tid + t * THREADS;
            if (i < BC) *(int4v*)&bs[i * 16] = breg[t];
        }
    };

    load_chunk(0);
    for (int ck = 0; ck < Cin; ck += 32) {
        __syncthreads();            // all waves done reading previous chunk
        store_chunk();
        __syncthreads();            // LDS visible
        if (ck + 32 < Cin) load_chunk(ck + 32);   // issue early; lands during MFMA

        #pragma unroll
        for (int s9 = 0; s9 < 9; ++s9) {
            const int dy = s9 / 3, dx = s9 % 3;
            int4v a[R];
            #pragma unroll
            for (int r = 0; r < R; ++r)
                a[r] = *(const int4v*)&xs[(p0[r] + dy * 18 + dx) * 48 + half * 16];
            #pragma unroll
            for (int u = 0; u < 4; ++u) {
                if (u < S_NT[s9]) {
                    int4v b = *(const int4v*)&bs[S_TAP[s9][u] * 1024 + lane * 16];
                    const int p = S_PAR[s9][u];
                    #pragma unroll
                    for (int r = 0; r < R; ++r)
                        acc[r][p] = __builtin_amdgcn_mfma_i32_32x32x32_i8(a[r], b, acc[r][p], 0, 0, 0);
                }
            }
        }
    }

    // ----- quant epilogue (exact fp32 op sequence; proven absmax 0.0) --------
    const int dv = dvds[layer];
    float add1 = ldexpf(1.0f, dv - 10);
    float inv1 = ldexpf(1.0f, -(dv - 9));
    const float relu = relus[layer];
    const int sk = (layer == 1) ? 4 : 3;
    const float bitsv = ldexpf(1.0f, bitsp[0]) - 1.0f;
    float clp, scl;
    {
        #pragma clang fp contract(off)
        clp = rintf(bitsv / relu * 33554432.0f);
        scl = floorf((relu + ldexpf(1.0f, sk - 1)) * ldexpf(1.0f, -sk));
    }
    float add2 = ldexpf(1.0f, 24 - sk);
    float inv2 = ldexpf(1.0f, -(25 - sk));

    const int co = n0 + (lane & 31);
    float bq = rintf(bias[co]);
    float mm = muls[co];
    int fullp[4];
    #pragma unroll
    for (int p = 0; p < 4; ++p) fullp[p] = tsum[p * Cout + co];

    const int Wout = Wq * 2;

    #pragma unroll
    for (int r = 0; r < R; ++r) {
        #pragma unroll
        for (int p = 0; p < 4; ++p) {
            const int py = p >> 1, px = p & 1;
            #pragma unroll
            for (int reg = 0; reg < 16; ++reg) {
                const int mrow = (reg & 3) + 8 * (reg >> 2) + 4 * (lane >> 5);
                const int qy = qy0 + (wid * R + r) * 2 + (mrow >> 4);
                const int qx = qx0 + (mrow & 15);
                float v = (float)(acc[r][p][reg] + 128 * fullp[p]);
                {
                    #pragma clang fp contract(off)
                    v = (v + bq) * mm;
                    v = floorf((v + add1) * inv1);
                    v = fminf(fmaxf(v, 0.0f), clp);
                    v = floorf((v * scl + add2) * inv2);
                }
                const int oy = 2 * qy + py, ox = 2 * qx + px;
                outp[((size_t)oy * Wout + ox) * Cout + co] = (signed char)((int)v - 128);
            }
        }
    }
}

// Final layer v6: N = (parity,co) columns, 1 MFMA per shift, R=2, MW=8,
// register-prefetch pipeline.
__global__ __launch_bounds__(512)
void deconv_final_v6(const signed char* __restrict__ xin, const signed char* __restrict__ wpk,
                     const float* __restrict__ bias, const float* __restrict__ muls,
                     const int* __restrict__ tsum, const int* __restrict__ dvds,
                     int Cin, int Hq, int Wq, float* __restrict__ outp) {
    constexpr int R = 2, MW = 8;
    constexpr int NROW = MW * R * 2 + 2;   // 34
    constexpr int NPIX = NROW * 18;        // 612
    constexpr int THREADS = 512;
    constexpr int XC = NPIX * 2;           // 1224
    constexpr int XI = (XC + THREADS - 1) / THREADS;   // 3
    constexpr int BC = 576;
    constexpr int BI = (BC + THREADS - 1) / THREADS;   // 2

    __shared__ __align__(16) signed char xs[NPIX * 48];
    __shared__ __align__(16) signed char bs[9216];

    const int tid  = threadIdx.x;
    const int lane = tid & 63;
    const int wid  = tid >> 6;
    const int qx0  = blockIdx.y * 16;
    const int qy0  = blockIdx.z * (MW * R * 2);

    int16v acc[R];
    #pragma unroll
    for (int r = 0; r < R; ++r)
        #pragma unroll
        for (int e = 0; e < 16; ++e) acc[r][e] = 0;

    const int half   = lane >> 5;
    const int rowbit = (lane >> 4) & 1;
    const int col    = lane & 15;
    int p0[R];
    #pragma unroll
    for (int r = 0; r < R; ++r)
        p0[r] = ((wid * R + r) * 2 + rowbit) * 18 + col;

    int4v xreg[XI], breg[BI];

    auto load_chunk = [&](int ck) {
        const signed char* wslab = wpk + (size_t)(ck >> 5) * 9216;
        #pragma unroll
        for (int t = 0; t < XI; ++t) {
            int i = tid + t * THREADS;
            if (i < XC) {
                int pix = i >> 1, g = i & 1;
                int rr = pix / 18, cc = pix - rr * 18;
                int y = qy0 - 1 + rr, xx = qx0 - 1 + cc;
                int4v v = {(int)0x80808080, (int)0x80808080,
                           (int)0x80808080, (int)0x80808080};
                if ((unsigned)y < (unsigned)Hq && (unsigned)xx < (unsigned)Wq)
                    v = *(const int4v*)&xin[((size_t)y * Wq + xx) * Cin + ck + g * 16];
                xreg[t] = v;
            }
        }
        #pragma unroll
        for (int t = 0; t < BI; ++t) {
            int i = tid + t * THREADS;
            if (i < BC) breg[t] = *(const int4v*)&wslab[(size_t)i * 16];
        }
    };
    auto store_chunk = [&]() {
        #pragma unroll
        for (int t = 0; t < XI; ++t) {
            int i = tid + t * THREADS;
            if (i < XC) {
                int pix = i >> 1, g = i & 1;
                *(int4v*)&xs[pix * 48 + g * 16] = xreg[t];
            }
        }
        #pragma unroll
        for (int t = 0; t < BI; ++t) {
            int i = tid + t * THREADS;
            if (i < BC) *(int4v*)&bs[i * 16] = breg[t];
        }
    };

    load_chunk(0);
    for (int ck = 0; ck < Cin; ck += 32) {
        __syncthreads();
        store_chunk();
        __syncthreads();
        if (ck + 32 < Cin) load_chunk(ck + 32);

        #pragma unroll
        for (int s9 = 0; s9 < 9; ++s9) {
            const int dy = s9 / 3, dx = s9 % 3;
            int4v b = *(const int4v*)&bs[s9 * 1024 + lane * 16];
            #pragma unroll
            for (int r = 0; r < R; ++r) {
                int4v a = *(const int4v*)&xs[(p0[r] + dy * 18 + dx) * 48 + half * 16];
                acc[r] = __builtin_amdgcn_mfma_i32_32x32x32_i8(a, b, acc[r], 0, 0, 0);
            }
        }
    }

    const int dv = dvds[3];
    const float add1 = ldexpf(1.0f, dv - 9);
    const float inv1 = ldexpf(1.0f, -(dv - 8));

    const int coln = lane & 31;
    const int co = coln & 7;
    const int p  = coln >> 3;
    const int py = p >> 1, px = p & 1;
    const bool valid = (co < 3);
    float bq = 0.f, mm = 0.f;
    int fp = 0;
    if (valid) { bq = rintf(bias[co]); mm = muls[co]; fp = tsum[p * 3 + co]; }

    const int Wout = Wq * 2, Hout = Hq * 2;
    #pragma unroll
    for (int r = 0; r < R; ++r) {
        #pragma unroll
        for (int reg = 0; reg < 16; ++reg) {
            const int mrow = (reg & 3) + 8 * (reg >> 2) + 4 * (lane >> 5);
            const int qy = qy0 + (wid * R + r) * 2 + (mrow >> 4);
            const int qx = qx0 + (mrow & 15);
            float v = (float)(acc[r][reg] + 128 * fp);
            {
                #pragma clang fp contract(off)
                v = (v + bq) * mm;
                v = floorf((v + add1) * inv1);
                v = v / 255.0f;
            }
            if (valid) {
                const int oy = 2 * qy + py, ox = 2 * qx + px;
                outp[((size_t)co * Hout + oy) * Wout + ox] = v;
            }
        }
    }
}

extern "C" void kernel_launch(void* const* d_in, const int* in_sizes, int n_in,
                              void* d_out, int out_size, void* d_ws, size_t ws_size,
                              hipStream_t stream) {
    const float* x  = (const float*)d_in[0];
    const float* w1 = (const float*)d_in[1];
    const float* b1 = (const float*)d_in[2];
    const float* w2 = (const float*)d_in[3];
    const float* b2 = (const float*)d_in[4];
    const float* w3 = (const float*)d_in[5];
    const float* b3 = (const float*)d_in[6];
    const float* w4 = (const float*)d_in[7];
    const float* b4 = (const float*)d_in[8];
    const float* m0 = (const float*)d_in[9];
    const float* m1 = (const float*)d_in[10];
    const float* m2 = (const float*)d_in[11];
    const float* m3 = (const float*)d_in[12];
    const float* relus = (const float*)d_in[13];
    const int* dvds = (const int*)d_in[14];
    const int* bitsp = (const int*)d_in[15];

    signed char* wsb = (signed char*)d_ws;
    size_t o = 0;
    signed char* wpk1 = wsb + o; o += (size_t)10 * 6 * 25600;   // 1,536,000
    signed char* wpk2 = wsb + o; o += (size_t)6 * 6 * 25600;    //   921,600
    signed char* wpk3 = wsb + o; o += (size_t)6 * 6 * 25600;
    signed char* wpk4 = wsb + o; o += (size_t)6 * 9216;         //    55,296
    int* ts1 = (int*)(wsb + o); o += 4 * 192 * 4;
    int* ts2 = (int*)(wsb + o); o += 4 * 192 * 4;
    int* ts3 = (int*)(wsb + o); o += 4 * 192 * 4;
    int* ts4 = (int*)(wsb + o); o += 4 * 4 * 4;
    o = (o + 15) & ~(size_t)15;
    signed char* xh = wsb + o; o += (size_t)48 * 48 * 320;
    signed char* a1 = wsb + o; o += (size_t)96 * 96 * 192;
    signed char* a2 = wsb + o; o += (size_t)192 * 192 * 192;
    signed char* a3 = wsb + o; o += (size_t)384 * 384 * 192;

    convert_x_t<<<dim3(36, 5), 256, 0, stream>>>(x, xh, 320, 48 * 48);
    pack3<<<dim3(240, 3), 256, 0, stream>>>(w1, w2, w3, wpk1, wpk2, wpk3);
    pack_w4_i8<<<(6 * 9 * 1024 + 255) / 256, 256, 0, stream>>>(w4, wpk4);
    tap4<<<dim3(768, 4), 64, 0, stream>>>(w1, w2, w3, w4, ts1, ts2, ts3, ts4);

    // layer 1: 48x48x320 -> 96x96x192   (16x16-quad tiles, 54 blocks, 256 thr)
    deconv_v6<4><<<dim3(6, 3, 3), 256, 0, stream>>>(
        xh, wpk1, b1, m0, ts1, relus, dvds, bitsp, 0, 320, 192, 6, 48, 48, a1);
    // layer 2: 96x96x192 -> 192x192x192 (216 blocks, 256 thr)
    deconv_v6<4><<<dim3(6, 6, 6), 256, 0, stream>>>(
        a1, wpk2, b2, m1, ts2, relus, dvds, bitsp, 1, 192, 192, 6, 96, 96, a2);
    // layer 3: 192x192x192 -> 384x384x192 (32x16-quad tiles, 432 blocks, 512 thr)
    deconv_v6<8><<<dim3(6, 12, 6), 512, 0, stream>>>(
        a2, wpk3, b3, m2, ts3, relus, dvds, bitsp, 2, 192, 192, 6, 192, 192, a3);
    // layer 4: 384x384x192 -> 3x768x768 (final, f32 NCHW, /255; 288 blocks, 512 thr)
    deconv_final_v6<<<dim3(1, 24, 12), 512, 0, stream>>>(
        a3, wpk4, b4, m3, ts4, dvds, 192, 384, 384, (float*)d_out);
}

// Round 10
// 224.420 us; speedup vs baseline: 1.4323x; 1.0499x over previous
//
#include <hip/hip_runtime.h>
#include <cmath>

// ---------------------------------------------------------------------------
// g_s: 4x chained conv_transpose2d(k=5,s=2,p=2,op=1) + integer quant epilogue.
// Hermite: sum_j floor((round(w)+j)/split) == round(w) -> one conv per layer.
// Exact i8: weights round(w) in [-127,127]; activations (x-128) in i8; OOB
// halo = -128 so conv_i8 = conv_ref(x) - 128*tapsum[parity][co] (exact i32).
// v7: parity-split wave pairs. v6's acc[2][4]=128 AGPRs forced 2 waves/SIMD
// (244 regs/wave); splitting the 4 parities across a wave pair (role0: EE+OO
// = 13 taps, role1: EO+OE = 12 taps) halves acc to 64, launch_bounds(.,3)
// gives 3 waves/SIMD + register headroom for ds_read pipelining. B-reads
// stay non-duplicated (25/pair); A-reads duplicate x2 (LDS has slack).
// ---------------------------------------------------------------------------

typedef int int4v  __attribute__((ext_vector_type(4)));
typedef int int16v __attribute__((ext_vector_type(16)));

// tap id -> (ky,kx). Taps 0-8: EE; 9-14: EO; 15-20: OE; 21-24: OO.
__device__ __forceinline__ void tap_to_k(int t, int& ky, int& kx) {
    if (t < 9)       { int dy = t/3,  dx = t%3;                   ky = 4-2*dy; kx = 4-2*dx; }
    else if (t < 15) { int u = t-9;   int dy = u/2, dx = 1+(u&1);  ky = 4-2*dy; kx = 5-2*dx; }
    else if (t < 21) { int u = t-15;  int dy = 1+u/3, dx = u%3;    ky = 5-2*dy; kx = 4-2*dx; }
    else             { int u = t-21;  int dy = 1+u/2, dx = 1+(u&1); ky = 5-2*dy; kx = 5-2*dx; }
}

// f32 NCHW -> i8 (x-128) NHWC via LDS transpose (both sides coalesced)
__global__ __launch_bounds__(256)
void convert_x_t(const float* __restrict__ x, signed char* __restrict__ xh,
                 int C, int HW) {
    __shared__ float t[64][65];
    const int p0 = blockIdx.x * 64;
    const int c0 = blockIdx.y * 64;
    const int pL = threadIdx.x & 63;
    const int r0 = threadIdx.x >> 6;  // 0..3
    #pragma unroll
    for (int k = 0; k < 16; ++k) {
        int ciL = r0 * 16 + k;
        t[ciL][pL] = x[(size_t)(c0 + ciL) * HW + p0 + pL];
    }
    __syncthreads();
    #pragma unroll
    for (int k = 0; k < 16; ++k) {
        int pL2 = r0 * 16 + k;
        xh[(size_t)(p0 + pL2) * C + c0 + pL] = (signed char)((int)t[pL][pL2] - 128);
    }
}

// Coalesced pack for layers 1-3: one thread per (ci,co):
// byte addr = ((qs*NT + nb)*25 + t)*1024 + lane*16 + j
__global__ __launch_bounds__(256)
void pack3(const float* __restrict__ w1, const float* __restrict__ w2,
           const float* __restrict__ w3,
           signed char* __restrict__ p1, signed char* __restrict__ p2,
           signed char* __restrict__ p3) {
    const int layer = blockIdx.y;
    const float* w = (layer == 0) ? w1 : (layer == 1) ? w2 : w3;
    signed char* out = (layer == 0) ? p1 : (layer == 1) ? p2 : p3;
    const int Cin = (layer == 0) ? 320 : 192;
    const int Cout = 192, NT = 6;
    int idx = blockIdx.x * 256 + threadIdx.x;
    if (idx >= Cin * Cout) return;
    const int co = idx % Cout, ci = idx / Cout;
    const float* wr = w + (size_t)(ci * Cout + co) * 25;
    float v[25];
    #pragma unroll
    for (int k = 0; k < 25; ++k) {
        float t = rintf(wr[k]);
        v[k] = fminf(fmaxf(t, -128.0f), 127.0f);
    }
    const int qs = ci >> 5, half = (ci >> 4) & 1, j = ci & 15;
    const int nb = co >> 5, lane = half * 32 + (co & 31);
    size_t base = ((size_t)(qs * NT + nb) * 25) * 1024 + lane * 16 + j;
    #pragma unroll
    for (int t = 0; t < 25; ++t) {
        int ky, kx; tap_to_k(t, ky, kx);
        out[base + (size_t)t * 1024] = (signed char)(int)v[ky * 5 + kx];
    }
}

// final-layer pack: N-dim = (parity,co): column c = p*8+co (co<3 live).
__global__ void pack_w4_i8(const float* __restrict__ w, signed char* __restrict__ wpk) {
    int idx = blockIdx.x * blockDim.x + threadIdx.x;
    if (idx >= 6 * 9 * 64 * 16) return;
    int j    = idx & 15;
    int lane = (idx >> 4) & 63;
    int rem  = idx >> 10;
    int s9   = rem % 9;
    int qs   = rem / 9;
    int col  = lane & 31;
    int co   = col & 7;
    int p    = col >> 3;
    int py = p >> 1, px = p & 1;
    int dy = s9 / 3, dx = s9 % 3;
    int ci = qs * 32 + ((lane >> 5) << 4) + j;
    bool part = (py == 0 || dy >= 1) && (px == 0 || dx >= 1);
    float v = 0.0f;
    if (co < 3 && part) {
        int ky = py ? 5 - 2 * dy : 4 - 2 * dy;
        int kx = px ? 5 - 2 * dx : 4 - 2 * dx;
        v = rintf(w[(size_t)(ci * 3 + co) * 25 + ky * 5 + kx]);
        v = fminf(fmaxf(v, -128.0f), 127.0f);
    }
    wpk[idx] = (signed char)(int)v;
}

// fused tapsum: tapsum[p][co] = sum_{ky%2==py,kx%2==px} sum_ci round(w) (i32)
__global__ __launch_bounds__(64)
void tap4(const float* __restrict__ w1, const float* __restrict__ w2,
          const float* __restrict__ w3, const float* __restrict__ w4,
          int* __restrict__ t1, int* __restrict__ t2,
          int* __restrict__ t3, int* __restrict__ t4) {
    const int layer = blockIdx.y;
    const float* w = (layer == 0) ? w1 : (layer == 1) ? w2 : (layer == 2) ? w3 : w4;
    int* ts = (layer == 0) ? t1 : (layer == 1) ? t2 : (layer == 2) ? t3 : t4;
    const int Cin = (layer == 0) ? 320 : 192;
    const int Cout = (layer == 3) ? 3 : 192;
    const int i = blockIdx.x;
    if (i >= 4 * Cout) return;
    const int co = i % Cout, p = i / Cout;
    const int py = p >> 1, px = p & 1;
    const int nky = (5 - py + 1) >> 1;
    const int nkx = (5 - px + 1) >> 1;
    const int ntap = nky * nkx;
    int s = 0;
    for (int idx = threadIdx.x; idx < Cin * ntap; idx += 64) {
        const int ci = idx / ntap;
        const int u  = idx - ci * ntap;
        const int ky = py + 2 * (u / nkx);
        const int kx = px + 2 * (u % nkx);
        float v = rintf(w[(size_t)(ci * Cout + co) * 25 + ky * 5 + kx]);
        v = fminf(fmaxf(v, -128.0f), 127.0f);
        s += (int)v;
    }
    #pragma unroll
    for (int off = 32; off > 0; off >>= 1)
        s += __shfl_down(s, off, 64);
    if (threadIdx.x == 0) ts[i] = s;
}

// Per-role tap tables for parity-split (role0: EE(acc0)+OO(acc1);
// role1: EO(acc0)+OE(acc1)). Verified against the full S_TAP/S_PAR map.
__device__ __forceinline__ constexpr int role_nt(int role, int s9) {
    constexpr int NT0[9] = {1,1,1,1,2,2,1,2,2};
    constexpr int NT1[9] = {0,1,1,1,2,2,1,2,2};
    return role == 0 ? NT0[s9] : NT1[s9];
}
__device__ __forceinline__ constexpr int role_tap(int role, int s9, int u) {
    constexpr int T0[9][2] = {{0,0},{1,0},{2,0},{3,0},{4,21},{5,22},{6,0},{7,23},{8,24}};
    constexpr int T1[9][2] = {{0,0},{9,0},{10,0},{15,0},{11,16},{12,17},{18,0},{13,19},{14,20}};
    return role == 0 ? T0[s9][u] : T1[s9][u];
}
__device__ __forceinline__ constexpr int role_acc(int role, int s9, int u) {
    constexpr int A0[9][2] = {{0,0},{0,0},{0,0},{0,0},{0,1},{0,1},{0,0},{0,1},{0,1}};
    constexpr int A1[9][2] = {{0,0},{0,0},{0,0},{1,0},{0,1},{0,1},{1,0},{0,1},{0,1}};
    return role == 0 ? A0[s9][u] : A1[s9][u];
}

template<int ROLE, int R>
__device__ __forceinline__ void compute_role(const signed char* xs, const signed char* bs,
                                             int16v (&acc)[R][2], const int (&p0)[R],
                                             int half, int lane) {
    #pragma unroll
    for (int s9 = 0; s9 < 9; ++s9) {
        if (role_nt(ROLE, s9) == 0) continue;
        const int dy = s9 / 3, dx = s9 % 3;
        int4v a[R];
        #pragma unroll
        for (int r = 0; r < R; ++r)
            a[r] = *(const int4v*)&xs[(p0[r] + dy * 18 + dx) * 48 + half * 16];
        #pragma unroll
        for (int u = 0; u < 2; ++u) {
            if (u < role_nt(ROLE, s9)) {
                int4v b = *(const int4v*)&bs[role_tap(ROLE, s9, u) * 1024 + lane * 16];
                const int ai = role_acc(ROLE, s9, u);
                #pragma unroll
                for (int r = 0; r < R; ++r)
                    acc[r][ai] = __builtin_amdgcn_mfma_i32_32x32x32_i8(a[r], b, acc[r][ai], 0, 0, 0);
            }
        }
    }
}

// Layers 1-3 v7: MW waves = MW/2 pairs x R=2 subtiles -> (MW*2) quad-rows x
// 16 cols x 32 co. Register-prefetch pipeline over KC=32 chunks.
template<int MW>
__global__ __launch_bounds__(MW * 64, 3)
void deconv_v7(const signed char* __restrict__ xin, const signed char* __restrict__ wpk,
               const float* __restrict__ bias, const float* __restrict__ muls,
               const int* __restrict__ tsum,
               const float* __restrict__ relus, const int* __restrict__ dvds,
               const int* __restrict__ bitsp,
               int layer, int Cin, int Cout, int NT, int Hq, int Wq,
               signed char* __restrict__ outp) {
    constexpr int R = 2;
    constexpr int PAIRS = MW / 2;
    constexpr int NROW = PAIRS * R * 2 + 2;
    constexpr int NPIX = NROW * 18;
    constexpr int THREADS = MW * 64;
    constexpr int XC = NPIX * 2;
    constexpr int XI = (XC + THREADS - 1) / THREADS;
    constexpr int BC = 1600;
    constexpr int BI = (BC + THREADS - 1) / THREADS;

    __shared__ __align__(16) signed char xs[NPIX * 48];
    __shared__ __align__(16) signed char bs[25600];

    const int tid  = threadIdx.x;
    const int lane = tid & 63;
    const int wid  = tid >> 6;
    const int pairId = wid >> 1;
    const int role   = wid & 1;
    const int qx0  = blockIdx.y * 16;
    const int qy0  = blockIdx.z * (PAIRS * R * 2);
    const int nb   = blockIdx.x;
    const int n0   = nb * 32;

    int16v acc[R][2];
    #pragma unroll
    for (int r = 0; r < R; ++r)
        #pragma unroll
        for (int p = 0; p < 2; ++p)
            #pragma unroll
            for (int e = 0; e < 16; ++e) acc[r][p][e] = 0;

    const int half   = lane >> 5;
    const int rowbit = (lane >> 4) & 1;
    const int col    = lane & 15;
    int p0[R];
    #pragma unroll
    for (int r = 0; r < R; ++r)
        p0[r] = ((pairId * R + r) * 2 + rowbit) * 18 + col;

    int4v xreg[XI], breg[BI];

    auto load_chunk = [&](int ck) {
        const signed char* wslab = wpk + (size_t)((ck >> 5) * NT + nb) * 25600;
        #pragma unroll
        for (int t = 0; t < XI; ++t) {
            int i = tid + t * THREADS;
            if (i < XC) {
                int pix = i >> 1, g = i & 1;
                int rr = pix / 18, cc = pix - rr * 18;
                int y = qy0 - 1 + rr, xx = qx0 - 1 + cc;
                int4v v = {(int)0x80808080, (int)0x80808080,
                           (int)0x80808080, (int)0x80808080};
                if ((unsigned)y < (unsigned)Hq && (unsigned)xx < (unsigned)Wq)
                    v = *(const int4v*)&xin[((size_t)y * Wq + xx) * Cin + ck + g * 16];
                xreg[t] = v;
            }
        }
        #pragma unroll
        for (int t = 0; t < BI; ++t) {
            int i = tid + t * THREADS;
            if (i < BC) breg[t] = *(const int4v*)&wslab[(size_t)i * 16];
        }
    };
    auto store_chunk = [&]() {
        #pragma unroll
        for (int t = 0; t < XI; ++t) {
            int i = tid + t * THREADS;
            if (i < XC) {
                int pix = i >> 1, g = i & 1;
                *(int4v*)&xs[pix * 48 + g * 16] = xreg[t];
            }
        }
        #pragma unroll
        for (int t = 0; t < BI; ++t) {
            int i = tid + t * THREADS;
            if (i < BC) *(int4v*)&bs[i * 16] = breg[t];
        }
    };

    load_chunk(0);
    for (int ck = 0; ck < Cin; ck += 32) {
        __syncthreads();            // all waves done reading previous chunk
        store_chunk();
        __syncthreads();            // LDS visible
        if (ck + 32 < Cin) load_chunk(ck + 32);   // lands during MFMA

        if (role == 0) compute_role<0, R>(xs, bs, acc, p0, half, lane);
        else           compute_role<1, R>(xs, bs, acc, p0, half, lane);
    }

    // ----- quant epilogue (exact fp32 op sequence; proven absmax 0.0) --------
    const int dv = dvds[layer];
    float add1 = ldexpf(1.0f, dv - 10);
    float inv1 = ldexpf(1.0f, -(dv - 9));
    const float relu = relus[layer];
    const int sk = (layer == 1) ? 4 : 3;
    const float bitsv = ldexpf(1.0f, bitsp[0]) - 1.0f;
    float clp, scl;
    {
        #pragma clang fp contract(off)
        clp = rintf(bitsv / relu * 33554432.0f);
        scl = floorf((relu + ldexpf(1.0f, sk - 1)) * ldexpf(1.0f, -sk));
    }
    float add2 = ldexpf(1.0f, 24 - sk);
    float inv2 = ldexpf(1.0f, -(25 - sk));

    const int co = n0 + (lane & 31);
    float bq = rintf(bias[co]);
    float mm = muls[co];
    // wave's two parities: role0 -> {EE=0, OO=3}; role1 -> {EO=1, OE=2}
    int pmap[2];
    pmap[0] = role == 0 ? 0 : 1;
    pmap[1] = role == 0 ? 3 : 2;
    int fullp[2];
    #pragma unroll
    for (int a = 0; a < 2; ++a) fullp[a] = tsum[pmap[a] * Cout + co];

    const int Wout = Wq * 2;

    #pragma unroll
    for (int r = 0; r < R; ++r) {
        #pragma unroll
        for (int a = 0; a < 2; ++a) {
            const int p = pmap[a];
            const int py = p >> 1, px = p & 1;
            #pragma unroll
            for (int reg = 0; reg < 16; ++reg) {
                const int mrow = (reg & 3) + 8 * (reg >> 2) + 4 * (lane >> 5);
                const int qy = qy0 + (pairId * R + r) * 2 + (mrow >> 4);
                const int qx = qx0 + (mrow & 15);
                float v = (float)(acc[r][a][reg] + 128 * fullp[a]);
                {
                    #pragma clang fp contract(off)
                    v = (v + bq) * mm;
                    v = floorf((v + add1) * inv1);
                    v = fminf(fmaxf(v, 0.0f), clp);
                    v = floorf((v * scl + add2) * inv2);
                }
                const int oy = 2 * qy + py, ox = 2 * qx + px;
                outp[((size_t)oy * Wout + ox) * Cout + co] = (signed char)((int)v - 128);
            }
        }
    }
}

// Final layer: N = (parity,co) columns, 1 MFMA per shift, R=2, MW=8,
// register-prefetch pipeline; acc is only 32 regs so just raise occupancy.
__global__ __launch_bounds__(512, 3)
void deconv_final_v7(const signed char* __restrict__ xin, const signed char* __restrict__ wpk,
                     const float* __restrict__ bias, const float* __restrict__ muls,
                     const int* __restrict__ tsum, const int* __restrict__ dvds,
                     int Cin, int Hq, int Wq, float* __restrict__ outp) {
    constexpr int R = 2, MW = 8;
    constexpr int NROW = MW * R * 2 + 2;   // 34
    constexpr int NPIX = NROW * 18;        // 612
    constexpr int THREADS = 512;
    constexpr int XC = NPIX * 2;           // 1224
    constexpr int XI = (XC + THREADS - 1) / THREADS;   // 3
    constexpr int BC = 576;
    constexpr int BI = (BC + THREADS - 1) / THREADS;   // 2

    __shared__ __align__(16) signed char xs[NPIX * 48];
    __shared__ __align__(16) signed char bs[9216];

    const int tid  = threadIdx.x;
    const int lane = tid & 63;
    const int wid  = tid >> 6;
    const int qx0  = blockIdx.y * 16;
    const int qy0  = blockIdx.z * (MW * R * 2);

    int16v acc[R];
    #pragma unroll
    for (int r = 0; r < R; ++r)
        #pragma unroll
        for (int e = 0; e < 16; ++e) acc[r][e] = 0;

    const int half   = lane >> 5;
    const int rowbit = (lane >> 4) & 1;
    const int col    = lane & 15;
    int p0[R];
    #pragma unroll
    for (int r = 0; r < R; ++r)
        p0[r] = ((wid * R + r) * 2 + rowbit) * 18 + col;

    int4v xreg[XI], breg[BI];

    auto load_chunk = [&](int ck) {
        const signed char* wslab = wpk + (size_t)(ck >> 5) * 9216;
        #pragma unroll
        for (int t = 0; t < XI; ++t) {
            int i = tid + t * THREADS;
            if (i < XC) {
                int pix = i >> 1, g = i & 1;
                int rr = pix / 18, cc = pix - rr * 18;
                int y = qy0 - 1 + rr, xx = qx0 - 1 + cc;
                int4v v = {(int)0x80808080, (int)0x80808080,
                           (int)0x80808080, (int)0x80808080};
                if ((unsigned)y < (unsigned)Hq && (unsigned)xx < (unsigned)Wq)
                    v = *(const int4v*)&xin[((size_t)y * Wq + xx) * Cin + ck + g * 16];
                xreg[t] = v;
            }
        }
        #pragma unroll
        for (int t = 0; t < BI; ++t) {
            int i = tid + t * THREADS;
            if (i < BC) breg[t] = *(const int4v*)&wslab[(size_t)i * 16];
        }
    };
    auto store_chunk = [&]() {
        #pragma unroll
        for (int t = 0; t < XI; ++t) {
            int i = tid + t * THREADS;
            if (i < XC) {
                int pix = i >> 1, g = i & 1;
                *(int4v*)&xs[pix * 48 + g * 16] = xreg[t];
            }
        }
        #pragma unroll
        for (int t = 0; t < BI; ++t) {
            int i = tid + t * THREADS;
            if (i < BC) *(int4v*)&bs[i * 16] = breg[t];
        }
    };

    load_chunk(0);
    for (int ck = 0; ck < Cin; ck += 32) {
        __syncthreads();
        store_chunk();
        __syncthreads();
        if (ck + 32 < Cin) load_chunk(ck + 32);

        #pragma unroll
        for (int s9 = 0; s9 < 9; ++s9) {
            const int dy = s9 / 3, dx = s9 % 3;
            int4v b = *(const int4v*)&bs[s9 * 1024 + lane * 16];
            #pragma unroll
            for (int r = 0; r < R; ++r) {
                int4v a = *(const int4v*)&xs[(p0[r] + dy * 18 + dx) * 48 + half * 16];
                acc[r] = __builtin_amdgcn_mfma_i32_32x32x32_i8(a, b, acc[r], 0, 0, 0);
            }
        }
    }

    const int dv = dvds[3];
    const float add1 = ldexpf(1.0f, dv - 9);
    const float inv1 = ldexpf(1.0f, -(dv - 8));

    const int coln = lane & 31;
    const int co = coln & 7;
    const int p  = coln >> 3;
    const int py = p >> 1, px = p & 1;
    const bool valid = (co < 3);
    float bq = 0.f, mm = 0.f;
    int fp = 0;
    if (valid) { bq = rintf(bias[co]); mm = muls[co]; fp = tsum[p * 3 + co]; }

    const int Wout = Wq * 2, Hout = Hq * 2;
    #pragma unroll
    for (int r = 0; r < R; ++r) {
        #pragma unroll
        for (int reg = 0; reg < 16; ++reg) {
            const int mrow = (reg & 3) + 8 * (reg >> 2) + 4 * (lane >> 5);
            const int qy = qy0 + (wid * R + r) * 2 + (mrow >> 4);
            const int qx = qx0 + (mrow & 15);
            float v = (float)(acc[r][reg] + 128 * fp);
            {
                #pragma clang fp contract(off)
                v = (v + bq) * mm;
                v = floorf((v + add1) * inv1);
                v = v / 255.0f;
            }
            if (valid) {
                const int oy = 2 * qy + py, ox = 2 * qx + px;
                outp[((size_t)co * Hout + oy) * Wout + ox] = v;
            }
        }
    }
}

extern "C" void kernel_launch(void* const* d_in, const int* in_sizes, int n_in,
                              void* d_out, int out_size, void* d_ws, size_t ws_size,
                              hipStream_t stream) {
    const float* x  = (const float*)d_in[0];
    const float* w1 = (const float*)d_in[1];
    const float* b1 = (const float*)d_in[2];
    const float* w2 = (const float*)d_in[3];
    const float* b2 = (const float*)d_in[4];
    const float* w3 = (const float*)d_in[5];
    const float* b3 = (const float*)d_in[6];
    const float* w4 = (const float*)d_in[7];
    const float* b4 = (const float*)d_in[8];
    const float* m0 = (const float*)d_in[9];
    const float* m1 = (const float*)d_in[10];
    const float* m2 = (const float*)d_in[11];
    const float* m3 = (const float*)d_in[12];
    const float* relus = (const float*)d_in[13];
    const int* dvds = (const int*)d_in[14];
    const int* bitsp = (const int*)d_in[15];

    signed char* wsb = (signed char*)d_ws;
    size_t o = 0;
    signed char* wpk1 = wsb + o; o += (size_t)10 * 6 * 25600;   // 1,536,000
    signed char* wpk2 = wsb + o; o += (size_t)6 * 6 * 25600;    //   921,600
    signed char* wpk3 = wsb + o; o += (size_t)6 * 6 * 25600;
    signed char* wpk4 = wsb + o; o += (size_t)6 * 9216;         //    55,296
    int* ts1 = (int*)(wsb + o); o += 4 * 192 * 4;
    int* ts2 = (int*)(wsb + o); o += 4 * 192 * 4;
    int* ts3 = (int*)(wsb + o); o += 4 * 192 * 4;
    int* ts4 = (int*)(wsb + o); o += 4 * 4 * 4;
    o = (o + 15) & ~(size_t)15;
    signed char* xh = wsb + o; o += (size_t)48 * 48 * 320;
    signed char* a1 = wsb + o; o += (size_t)96 * 96 * 192;
    signed char* a2 = wsb + o; o += (size_t)192 * 192 * 192;
    signed char* a3 = wsb + o; o += (size_t)384 * 384 * 192;

    convert_x_t<<<dim3(36, 5), 256, 0, stream>>>(x, xh, 320, 48 * 48);
    pack3<<<dim3(240, 3), 256, 0, stream>>>(w1, w2, w3, wpk1, wpk2, wpk3);
    pack_w4_i8<<<(6 * 9 * 1024 + 255) / 256, 256, 0, stream>>>(w4, wpk4);
    tap4<<<dim3(768, 4), 64, 0, stream>>>(w1, w2, w3, w4, ts1, ts2, ts3, ts4);

    // layer 1: 48x48x320 -> 96x96x192   (8-row tiles, 108 blocks, 256 thr)
    deconv_v7<4><<<dim3(6, 3, 6), 256, 0, stream>>>(
        xh, wpk1, b1, m0, ts1, relus, dvds, bitsp, 0, 320, 192, 6, 48, 48, a1);
    // layer 2: 96x96x192 -> 192x192x192 (16-row tiles, 216 blocks, 512 thr)
    deconv_v7<8><<<dim3(6, 6, 6), 512, 0, stream>>>(
        a1, wpk2, b2, m1, ts2, relus, dvds, bitsp, 1, 192, 192, 6, 96, 96, a2);
    // layer 3: 192x192x192 -> 384x384x192 (16-row tiles, 864 blocks, 512 thr)
    deconv_v7<8><<<dim3(6, 12, 12), 512, 0, stream>>>(
        a2, wpk3, b3, m2, ts3, relus, dvds, bitsp, 2, 192, 192, 6, 192, 192, a3);
    // layer 4: 384x384x192 -> 3x768x768 (final, f32 NCHW, /255; 288 blocks)
    deconv_final_v7<<<dim3(1, 24, 12), 512, 0, stream>>>(
        a3, wpk4, b4, m3, ts4, dvds, 192, 384, 384, (float*)d_out);
}

// Round 11
// 211.524 us; speedup vs baseline: 1.5196x; 1.0610x over previous
//
#include <hip/hip_runtime.h>
#include <cmath>

// ---------------------------------------------------------------------------
// g_s: 4x chained conv_transpose2d(k=5,s=2,p=2,op=1) + integer quant epilogue.
// Hermite: sum_j floor((round(w)+j)/split) == round(w) -> one conv per layer.
// Exact i8: weights round(w) in [-127,127]; activations (x-128) in i8; OOB
// halo = -128 so conv_i8 = conv_ref(x) - 128*tapsum[parity][co] (exact i32).
// v8: (a) launch_bounds(512,4) -> <=128 unified regs -> 2 blocks/CU for L3
// (v7 measured 1 block/CU: acc 64 AGPR + 64 VGPR landed just over 128);
// (b) packA: LDS-staged coalesced weight packing + fused tapsum reduction
// (pack3 had 3.3MB scattered byte stores); (c) tap kernel only for w4.
// ---------------------------------------------------------------------------

typedef int int4v  __attribute__((ext_vector_type(4)));
typedef int int16v __attribute__((ext_vector_type(16)));

// tap id -> (ky,kx). Taps 0-8: EE; 9-14: EO; 15-20: OE; 21-24: OO.
__device__ __forceinline__ void tap_to_k(int t, int& ky, int& kx) {
    if (t < 9)       { int dy = t/3,  dx = t%3;                   ky = 4-2*dy; kx = 4-2*dx; }
    else if (t < 15) { int u = t-9;   int dy = u/2, dx = 1+(u&1);  ky = 4-2*dy; kx = 5-2*dx; }
    else if (t < 21) { int u = t-15;  int dy = 1+u/3, dx = u%3;    ky = 5-2*dy; kx = 4-2*dx; }
    else             { int u = t-21;  int dy = 1+u/2, dx = 1+(u&1); ky = 5-2*dy; kx = 5-2*dx; }
}

// f32 NCHW -> i8 (x-128) NHWC via LDS transpose; block(0,0) zeroes tapsums
__global__ __launch_bounds__(256)
void convert_x_t(const float* __restrict__ x, signed char* __restrict__ xh,
                 int* __restrict__ tsz, int ts_count, int C, int HW) {
    if (blockIdx.x == 0 && blockIdx.y == 0)
        for (int i = threadIdx.x; i < ts_count; i += 256) tsz[i] = 0;
    __shared__ float t[64][65];
    const int p0 = blockIdx.x * 64;
    const int c0 = blockIdx.y * 64;
    const int pL = threadIdx.x & 63;
    const int r0 = threadIdx.x >> 6;  // 0..3
    #pragma unroll
    for (int k = 0; k < 16; ++k) {
        int ciL = r0 * 16 + k;
        t[ciL][pL] = x[(size_t)(c0 + ciL) * HW + p0 + pL];
    }
    __syncthreads();
    #pragma unroll
    for (int k = 0; k < 16; ++k) {
        int pL2 = r0 * 16 + k;
        xh[(size_t)(p0 + pL2) * C + c0 + pL] = (signed char)((int)t[pL][pL2] - 128);
    }
}

// Fused pack+tapsum for layers 1-3. One block per 25600-B slab (qs,nb):
// stage the B-fragment slab in LDS (byte writes), copy out coalesced 16B;
// tapsum[p][co] reduced in LDS then one global atomicAdd per (p,co).
__global__ __launch_bounds__(256)
void packA(const float* __restrict__ w1, const float* __restrict__ w2,
           const float* __restrict__ w3,
           signed char* __restrict__ p1, signed char* __restrict__ p2,
           signed char* __restrict__ p3,
           int* __restrict__ t1, int* __restrict__ t2, int* __restrict__ t3) {
    const int layer = blockIdx.y;
    const float* w = (layer == 0) ? w1 : (layer == 1) ? w2 : w3;
    signed char* out = (layer == 0) ? p1 : (layer == 1) ? p2 : p3;
    int* ts = (layer == 0) ? t1 : (layer == 1) ? t2 : t3;
    const int Cout = 192;
    const int s = blockIdx.x;
    if (layer > 0 && s >= 36) return;
    const int qs = s / 6, nb = s % 6;

    __shared__ __align__(16) signed char ls[25600];
    __shared__ int lsum[4][32];
    if (threadIdx.x < 128) ((int*)lsum)[threadIdx.x] = 0;
    __syncthreads();

    #pragma unroll
    for (int k = 0; k < 4; ++k) {
        const int pidx = threadIdx.x + k * 256;   // 0..1023 = 32ci x 32co
        const int cil = pidx >> 5;
        const int col = pidx & 31;
        const int ci = qs * 32 + cil;
        const int co = nb * 32 + col;
        const float* wr = w + (size_t)(ci * Cout + co) * 25;
        const int half = cil >> 4, j = cil & 15;
        const int base = (half * 32 + col) * 16 + j;
        int psum[4] = {0, 0, 0, 0};
        #pragma unroll
        for (int t = 0; t < 25; ++t) {
            int ky, kx; tap_to_k(t, ky, kx);
            float v = rintf(wr[ky * 5 + kx]);
            v = fminf(fmaxf(v, -128.0f), 127.0f);
            int iv = (int)v;
            ls[t * 1024 + base] = (signed char)iv;
            psum[((ky & 1) << 1) | (kx & 1)] += iv;
        }
        #pragma unroll
        for (int p = 0; p < 4; ++p) atomicAdd(&lsum[p][col], psum[p]);
    }
    __syncthreads();

    signed char* dst = out + (size_t)s * 25600;
    for (int i = threadIdx.x; i < 1600; i += 256)
        *(int4v*)&dst[i * 16] = *(const int4v*)&ls[i * 16];
    if (threadIdx.x < 128) {
        const int p = threadIdx.x >> 5, col = threadIdx.x & 31;
        atomicAdd(&ts[p * Cout + nb * 32 + col], lsum[p][col]);
    }
}

// final-layer pack: N-dim = (parity,co): column c = p*8+co (co<3 live).
__global__ void pack_w4_i8(const float* __restrict__ w, signed char* __restrict__ wpk) {
    int idx = blockIdx.x * blockDim.x + threadIdx.x;
    if (idx >= 6 * 9 * 64 * 16) return;
    int j    = idx & 15;
    int lane = (idx >> 4) & 63;
    int rem  = idx >> 10;
    int s9   = rem % 9;
    int qs   = rem / 9;
    int col  = lane & 31;
    int co   = col & 7;
    int p    = col >> 3;
    int py = p >> 1, px = p & 1;
    int dy = s9 / 3, dx = s9 % 3;
    int ci = qs * 32 + ((lane >> 5) << 4) + j;
    bool part = (py == 0 || dy >= 1) && (px == 0 || dx >= 1);
    float v = 0.0f;
    if (co < 3 && part) {
        int ky = py ? 5 - 2 * dy : 4 - 2 * dy;
        int kx = px ? 5 - 2 * dx : 4 - 2 * dx;
        v = rintf(w[(size_t)(ci * 3 + co) * 25 + ky * 5 + kx]);
        v = fminf(fmaxf(v, -128.0f), 127.0f);
    }
    wpk[idx] = (signed char)(int)v;
}

// tapsum for w4 only: one 64-thread block per (p,co), 12 blocks.
__global__ __launch_bounds__(64)
void tap_w4(const float* __restrict__ w, int* __restrict__ ts) {
    const int Cin = 192, Cout = 3;
    const int i = blockIdx.x;            // p*3 + co
    const int co = i % Cout, p = i / Cout;
    const int py = p >> 1, px = p & 1;
    const int nky = (5 - py + 1) >> 1;
    const int nkx = (5 - px + 1) >> 1;
    const int ntap = nky * nkx;
    int s = 0;
    for (int idx = threadIdx.x; idx < Cin * ntap; idx += 64) {
        const int ci = idx / ntap;
        const int u  = idx - ci * ntap;
        const int ky = py + 2 * (u / nkx);
        const int kx = px + 2 * (u % nkx);
        float v = rintf(w[(size_t)(ci * Cout + co) * 25 + ky * 5 + kx]);
        v = fminf(fmaxf(v, -128.0f), 127.0f);
        s += (int)v;
    }
    #pragma unroll
    for (int off = 32; off > 0; off >>= 1)
        s += __shfl_down(s, off, 64);
    if (threadIdx.x == 0) ts[i] = s;
}

// Per-role tap tables for parity-split (role0: EE(acc0)+OO(acc1);
// role1: EO(acc0)+OE(acc1)). Verified against the full shift/tap/parity map.
__device__ __forceinline__ constexpr int role_nt(int role, int s9) {
    constexpr int NT0[9] = {1,1,1,1,2,2,1,2,2};
    constexpr int NT1[9] = {0,1,1,1,2,2,1,2,2};
    return role == 0 ? NT0[s9] : NT1[s9];
}
__device__ __forceinline__ constexpr int role_tap(int role, int s9, int u) {
    constexpr int T0[9][2] = {{0,0},{1,0},{2,0},{3,0},{4,21},{5,22},{6,0},{7,23},{8,24}};
    constexpr int T1[9][2] = {{0,0},{9,0},{10,0},{15,0},{11,16},{12,17},{18,0},{13,19},{14,20}};
    return role == 0 ? T0[s9][u] : T1[s9][u];
}
__device__ __forceinline__ constexpr int role_acc(int role, int s9, int u) {
    constexpr int A0[9][2] = {{0,0},{0,0},{0,0},{0,0},{0,1},{0,1},{0,0},{0,1},{0,1}};
    constexpr int A1[9][2] = {{0,0},{0,0},{0,0},{1,0},{0,1},{0,1},{1,0},{0,1},{0,1}};
    return role == 0 ? A0[s9][u] : A1[s9][u];
}

template<int ROLE, int R>
__device__ __forceinline__ void compute_role(const signed char* xs, const signed char* bs,
                                             int16v (&acc)[R][2], const int (&p0)[R],
                                             int half, int lane) {
    #pragma unroll
    for (int s9 = 0; s9 < 9; ++s9) {
        if (role_nt(ROLE, s9) == 0) continue;
        const int dy = s9 / 3, dx = s9 % 3;
        int4v a[R];
        #pragma unroll
        for (int r = 0; r < R; ++r)
            a[r] = *(const int4v*)&xs[(p0[r] + dy * 18 + dx) * 48 + half * 16];
        #pragma unroll
        for (int u = 0; u < 2; ++u) {
            if (u < role_nt(ROLE, s9)) {
                int4v b = *(const int4v*)&bs[role_tap(ROLE, s9, u) * 1024 + lane * 16];
                const int ai = role_acc(ROLE, s9, u);
                #pragma unroll
                for (int r = 0; r < R; ++r)
                    acc[r][ai] = __builtin_amdgcn_mfma_i32_32x32x32_i8(a[r], b, acc[r][ai], 0, 0, 0);
            }
        }
    }
}

// Layers 1-3: MW waves = MW/2 pairs x R=2 subtiles -> (MW*2) quad-rows x
// 16 cols x 32 co. Register-prefetch pipeline over KC=32 chunks.
// MW=8: launch_bounds(512,4) -> <=128 regs -> 2 blocks/CU.
template<int MW>
__global__ __launch_bounds__(MW * 64, MW == 8 ? 4 : 3)
void deconv_v8(const signed char* __restrict__ xin, const signed char* __restrict__ wpk,
               const float* __restrict__ bias, const float* __restrict__ muls,
               const int* __restrict__ tsum,
               const float* __restrict__ relus, const int* __restrict__ dvds,
               const int* __restrict__ bitsp,
               int layer, int Cin, int Cout, int NT, int Hq, int Wq,
               signed char* __restrict__ outp) {
    constexpr int R = 2;
    constexpr int PAIRS = MW / 2;
    constexpr int NROW = PAIRS * R * 2 + 2;
    constexpr int NPIX = NROW * 18;
    constexpr int THREADS = MW * 64;
    constexpr int XC = NPIX * 2;
    constexpr int XI = (XC + THREADS - 1) / THREADS;
    constexpr int BC = 1600;
    constexpr int BI = (BC + THREADS - 1) / THREADS;

    __shared__ __align__(16) signed char xs[NPIX * 48];
    __shared__ __align__(16) signed char bs[25600];

    const int tid  = threadIdx.x;
    const int lane = tid & 63;
    const int wid  = tid >> 6;
    const int pairId = wid >> 1;
    const int role   = wid & 1;
    const int qx0  = blockIdx.y * 16;
    const int qy0  = blockIdx.z * (PAIRS * R * 2);
    const int nb   = blockIdx.x;
    const int n0   = nb * 32;

    int16v acc[R][2];
    #pragma unroll
    for (int r = 0; r < R; ++r)
        #pragma unroll
        for (int p = 0; p < 2; ++p)
            #pragma unroll
            for (int e = 0; e < 16; ++e) acc[r][p][e] = 0;

    const int half   = lane >> 5;
    const int rowbit = (lane >> 4) & 1;
    const int col    = lane & 15;
    int p0[R];
    #pragma unroll
    for (int r = 0; r < R; ++r)
        p0[r] = ((pairId * R + r) * 2 + rowbit) * 18 + col;

    int4v xreg[XI], breg[BI];

    auto load_chunk = [&](int ck) {
        const signed char* wslab = wpk + (size_t)((ck >> 5) * NT + nb) * 25600;
        #pragma unroll
        for (int t = 0; t < XI; ++t) {
            int i = tid + t * THREADS;
            if (i < XC) {
                int pix = i >> 1, g = i & 1;
                int rr = pix / 18, cc = pix - rr * 18;
                int y = qy0 - 1 + rr, xx = qx0 - 1 + cc;
                int4v v = {(int)0x80808080, (int)0x80808080,
                           (int)0x80808080, (int)0x80808080};
                if ((unsigned)y < (unsigned)Hq && (unsigned)xx < (unsigned)Wq)
                    v = *(const int4v*)&xin[((size_t)y * Wq + xx) * Cin + ck + g * 16];
                xreg[t] = v;
            }
        }
        #pragma unroll
        for (int t = 0; t < BI; ++t) {
            int i = tid + t * THREADS;
            if (i < BC) breg[t] = *(const int4v*)&wslab[(size_t)i * 16];
        }
    };
    auto store_chunk = [&]() {
        #pragma unroll
        for (int t = 0; t < XI; ++t) {
            int i = tid + t * THREADS;
            if (i < XC) {
                int pix = i >> 1, g = i & 1;
                *(int4v*)&xs[pix * 48 + g * 16] = xreg[t];
            }
        }
        #pragma unroll
        for (int t = 0; t < BI; ++t) {
            int i = tid + t * THREADS;
            if (i < BC) *(int4v*)&bs[i * 16] = breg[t];
        }
    };

    load_chunk(0);
    for (int ck = 0; ck < Cin; ck += 32) {
        __syncthreads();            // all waves done reading previous chunk
        store_chunk();
        __syncthreads();            // LDS visible
        if (ck + 32 < Cin) load_chunk(ck + 32);   // lands during MFMA

        if (role == 0) compute_role<0, R>(xs, bs, acc, p0, half, lane);
        else           compute_role<1, R>(xs, bs, acc, p0, half, lane);
    }

    // ----- quant epilogue (exact fp32 op sequence; proven absmax 0.0) --------
    const int dv = dvds[layer];
    float add1 = ldexpf(1.0f, dv - 10);
    float inv1 = ldexpf(1.0f, -(dv - 9));
    const float relu = relus[layer];
    const int sk = (layer == 1) ? 4 : 3;
    const float bitsv = ldexpf(1.0f, bitsp[0]) - 1.0f;
    float clp, scl;
    {
        #pragma clang fp contract(off)
        clp = rintf(bitsv / relu * 33554432.0f);
        scl = floorf((relu + ldexpf(1.0f, sk - 1)) * ldexpf(1.0f, -sk));
    }
    float add2 = ldexpf(1.0f, 24 - sk);
    float inv2 = ldexpf(1.0f, -(25 - sk));

    const int co = n0 + (lane & 31);
    float bq = rintf(bias[co]);
    float mm = muls[co];
    // wave's two parities: role0 -> {EE=0, OO=3}; role1 -> {EO=1, OE=2}
    int pmap[2];
    pmap[0] = role == 0 ? 0 : 1;
    pmap[1] = role == 0 ? 3 : 2;
    int fullp[2];
    #pragma unroll
    for (int a = 0; a < 2; ++a) fullp[a] = tsum[pmap[a] * Cout + co];

    const int Wout = Wq * 2;

    #pragma unroll
    for (int r = 0; r < R; ++r) {
        #pragma unroll
        for (int a = 0; a < 2; ++a) {
            const int p = pmap[a];
            const int py = p >> 1, px = p & 1;
            #pragma unroll
            for (int reg = 0; reg < 16; ++reg) {
                const int mrow = (reg & 3) + 8 * (reg >> 2) + 4 * (lane >> 5);
                const int qy = qy0 + (pairId * R + r) * 2 + (mrow >> 4);
                const int qx = qx0 + (mrow & 15);
                float v = (float)(acc[r][a][reg] + 128 * fullp[a]);
                {
                    #pragma clang fp contract(off)
                    v = (v + bq) * mm;
                    v = floorf((v + add1) * inv1);
                    v = fminf(fmaxf(v, 0.0f), clp);
                    v = floorf((v * scl + add2) * inv2);
                }
                const int oy = 2 * qy + py, ox = 2 * qx + px;
                outp[((size_t)oy * Wout + ox) * Cout + co] = (signed char)((int)v - 128);
            }
        }
    }
}

// Final layer: N = (parity,co) columns, 1 MFMA per shift, R=2, MW=8,
// register-prefetch pipeline; acc 32 regs -> (512,4) is comfortable.
__global__ __launch_bounds__(512, 4)
void deconv_final_v8(const signed char* __restrict__ xin, const signed char* __restrict__ wpk,
                     const float* __restrict__ bias, const float* __restrict__ muls,
                     const int* __restrict__ tsum, const int* __restrict__ dvds,
                     int Cin, int Hq, int Wq, float* __restrict__ outp) {
    constexpr int R = 2, MW = 8;
    constexpr int NROW = MW * R * 2 + 2;   // 34
    constexpr int NPIX = NROW * 18;        // 612
    constexpr int THREADS = 512;
    constexpr int XC = NPIX * 2;           // 1224
    constexpr int XI = (XC + THREADS - 1) / THREADS;   // 3
    constexpr int BC = 576;
    constexpr int BI = (BC + THREADS - 1) / THREADS;   // 2

    __shared__ __align__(16) signed char xs[NPIX * 48];
    __shared__ __align__(16) signed char bs[9216];

    const int tid  = threadIdx.x;
    const int lane = tid & 63;
    const int wid  = tid >> 6;
    const int qx0  = blockIdx.y * 16;
    const int qy0  = blockIdx.z * (MW * R * 2);

    int16v acc[R];
    #pragma unroll
    for (int r = 0; r < R; ++r)
        #pragma unroll
        for (int e = 0; e < 16; ++e) acc[r][e] = 0;

    const int half   = lane >> 5;
    const int rowbit = (lane >> 4) & 1;
    const int col    = lane & 15;
    int p0[R];
    #pragma unroll
    for (int r = 0; r < R; ++r)
        p0[r] = ((wid * R + r) * 2 + rowbit) * 18 + col;

    int4v xreg[XI], breg[BI];

    auto load_chunk = [&](int ck) {
        const signed char* wslab = wpk + (size_t)(ck >> 5) * 9216;
        #pragma unroll
        for (int t = 0; t < XI; ++t) {
            int i = tid + t * THREADS;
            if (i < XC) {
                int pix = i >> 1, g = i & 1;
                int rr = pix / 18, cc = pix - rr * 18;
                int y = qy0 - 1 + rr, xx = qx0 - 1 + cc;
                int4v v = {(int)0x80808080, (int)0x80808080,
                           (int)0x80808080, (int)0x80808080};
                if ((unsigned)y < (unsigned)Hq && (unsigned)xx < (unsigned)Wq)
                    v = *(const int4v*)&xin[((size_t)y * Wq + xx) * Cin + ck + g * 16];
                xreg[t] = v;
            }
        }
        #pragma unroll
        for (int t = 0; t < BI; ++t) {
            int i = tid + t * THREADS;
            if (i < BC) breg[t] = *(const int4v*)&wslab[(size_t)i * 16];
        }
    };
    auto store_chunk = [&]() {
        #pragma unroll
        for (int t = 0; t < XI; ++t) {
            int i = tid + t * THREADS;
            if (i < XC) {
                int pix = i >> 1, g = i & 1;
                *(int4v*)&xs[pix * 48 + g * 16] = xreg[t];
            }
        }
        #pragma unroll
        for (int t = 0; t < BI; ++t) {
            int i = tid + t * THREADS;
            if (i < BC) *(int4v*)&bs[i * 16] = breg[t];
        }
    };

    load_chunk(0);
    for (int ck = 0; ck < Cin; ck += 32) {
        __syncthreads();
        store_chunk();
        __syncthreads();
        if (ck + 32 < Cin) load_chunk(ck + 32);

        #pragma unroll
        for (int s9 = 0; s9 < 9; ++s9) {
            const int dy = s9 / 3, dx = s9 % 3;
            int4v b = *(const int4v*)&bs[s9 * 1024 + lane * 16];
            #pragma unroll
            for (int r = 0; r < R; ++r) {
                int4v a = *(const int4v*)&xs[(p0[r] + dy * 18 + dx) * 48 + half * 16];
                acc[r] = __builtin_amdgcn_mfma_i32_32x32x32_i8(a, b, acc[r], 0, 0, 0);
            }
        }
    }

    const int dv = dvds[3];
    const float add1 = ldexpf(1.0f, dv - 9);
    const float inv1 = ldexpf(1.0f, -(dv - 8));

    const int coln = lane & 31;
    const int co = coln & 7;
    const int p  = coln >> 3;
    const int py = p >> 1, px = p & 1;
    const bool valid = (co < 3);
    float bq = 0.f, mm = 0.f;
    int fp = 0;
    if (valid) { bq = rintf(bias[co]); mm = muls[co]; fp = tsum[p * 3 + co]; }

    const int Wout = Wq * 2, Hout = Hq * 2;
    #pragma unroll
    for (int r = 0; r < R; ++r) {
        #pragma unroll
        for (int reg = 0; reg < 16; ++reg) {
            const int mrow = (reg & 3) + 8 * (reg >> 2) + 4 * (lane >> 5);
            const int qy = qy0 + (wid * R + r) * 2 + (mrow >> 4);
            const int qx = qx0 + (mrow & 15);
            float v = (float)(acc[r][reg] + 128 * fp);
            {
                #pragma clang fp contract(off)
                v = (v + bq) * mm;
                v = floorf((v + add1) * inv1);
                v = v / 255.0f;
            }
            if (valid) {
                const int oy = 2 * qy + py, ox = 2 * qx + px;
                outp[((size_t)co * Hout + oy) * Wout + ox] = v;
            }
        }
    }
}

extern "C" void kernel_launch(void* const* d_in, const int* in_sizes, int n_in,
                              void* d_out, int out_size, void* d_ws, size_t ws_size,
                              hipStream_t stream) {
    const float* x  = (const float*)d_in[0];
    const float* w1 = (const float*)d_in[1];
    const float* b1 = (const float*)d_in[2];
    const float* w2 = (const float*)d_in[3];
    const float* b2 = (const float*)d_in[4];
    const float* w3 = (const float*)d_in[5];
    const float* b3 = (const float*)d_in[6];
    const float* w4 = (const float*)d_in[7];
    const float* b4 = (const float*)d_in[8];
    const float* m0 = (const float*)d_in[9];
    const float* m1 = (const float*)d_in[10];
    const float* m2 = (const float*)d_in[11];
    const float* m3 = (const float*)d_in[12];
    const float* relus = (const float*)d_in[13];
    const int* dvds = (const int*)d_in[14];
    const int* bitsp = (const int*)d_in[15];

    signed char* wsb = (signed char*)d_ws;
    size_t o = 0;
    signed char* wpk1 = wsb + o; o += (size_t)10 * 6 * 25600;   // 1,536,000
    signed char* wpk2 = wsb + o; o += (size_t)6 * 6 * 25600;    //   921,600
    signed char* wpk3 = wsb + o; o += (size_t)6 * 6 * 25600;
    signed char* wpk4 = wsb + o; o += (size_t)6 * 9216;         //    55,296
    int* ts1 = (int*)(wsb + o); o += 4 * 192 * 4;
    int* ts2 = (int*)(wsb + o); o += 4 * 192 * 4;
    int* ts3 = (int*)(wsb + o); o += 4 * 192 * 4;
    int* ts4 = (int*)(wsb + o); o += 4 * 4 * 4;
    o = (o + 15) & ~(size_t)15;
    signed char* xh = wsb + o; o += (size_t)48 * 48 * 320;
    signed char* a1 = wsb + o; o += (size_t)96 * 96 * 192;
    signed char* a2 = wsb + o; o += (size_t)192 * 192 * 192;
    signed char* a3 = wsb + o; o += (size_t)384 * 384 * 192;

    const int ts_count = 4 * 192 * 3 + 4 * 4;   // ts1..ts4 contiguous ints

    convert_x_t<<<dim3(36, 5), 256, 0, stream>>>(x, xh, ts1, ts_count, 320, 48 * 48);
    packA<<<dim3(60, 3), 256, 0, stream>>>(w1, w2, w3, wpk1, wpk2, wpk3, ts1, ts2, ts3);
    pack_w4_i8<<<(6 * 9 * 1024 + 255) / 256, 256, 0, stream>>>(w4, wpk4);
    tap_w4<<<12, 64, 0, stream>>>(w4, ts4);

    // layer 1: 48x48x320 -> 96x96x192   (8-row tiles, 108 blocks, 256 thr)
    deconv_v8<4><<<dim3(6, 3, 6), 256, 0, stream>>>(
        xh, wpk1, b1, m0, ts1, relus, dvds, bitsp, 0, 320, 192, 6, 48, 48, a1);
    // layer 2: 96x96x192 -> 192x192x192 (16-row tiles, 216 blocks, 512 thr)
    deconv_v8<8><<<dim3(6, 6, 6), 512, 0, stream>>>(
        a1, wpk2, b2, m1, ts2, relus, dvds, bitsp, 1, 192, 192, 6, 96, 96, a2);
    // layer 3: 192x192x192 -> 384x384x192 (16-row tiles, 864 blocks, 512 thr)
    deconv_v8<8><<<dim3(6, 12, 12), 512, 0, stream>>>(
        a2, wpk3, b3, m2, ts3, relus, dvds, bitsp, 2, 192, 192, 6, 192, 192, a3);
    // layer 4: 384x384x192 -> 3x768x768 (final, f32 NCHW, /255; 288 blocks)
    deconv_final_v8<<<dim3(1, 24, 12), 512, 0, stream>>>(
        a3, wpk4, b4, m3, ts4, dvds, 192, 384, 384, (float*)d_out);
}